// Round 26
// baseline (153.597 us; speedup 1.0000x reference)
//
#include <hip/hip_runtime.h>
#include <cstddef>

// learned_qp_solver: B=4096, NUM=256, NC=1530, IND=260, H=1024, OUT=1786, 5 iters.
//
//   KKT solve closed form:  x = G v + (b_eq/z0) z,  G = C^{-1} - z z^T / z0 (symmetric)
//   MLP on matrix cores: v_mfma_f32_16x16x32_f16 (BK=32 GEMM1 / BK=64 GEMM2).
//   Solve: scaled split-fp16 (Gl,Vl x2048 dodge fp16 denormal flush in MFMA).
//   G build: U = L^{-1} at COMPILE TIME (constexpr quarters); gemm_g on MFMA.
//   qp_solve5: ALL 5 QP iterations in one kernel; init_v fused; 16 rows/block,
//   1024 threads (16 waves); full G hoist; 2 barriers/iter.
//   Round-26 theory (explains rounds 19-25: VGPR pinned at 64, hoist spilled
//   ~55MB regardless of launch_bounds/waves_per_eu): with 52.7KB LDS, TWO
//   1024-thread blocks fit per CU -> allocator targets 8 waves/EU -> 64-VGPR
//   budget -> spill. Fix: 32KB LDS pad (runtime-opaque keepalive) makes only
//   ONE block fit -> allocator's own occupancy math gives 4 waves/EU -> 128
//   VGPR budget -> the 64-reg G hoist is register-resident, zero spill.
//   Falsifiable: VGPR_Count 64->~128, WRITE_SIZE 55.5MB->4.3MB.
//
// ws layout (bytes), ~46.7 MB:
//   [0,          29360128)  NO   fp32 [B][1792]
//   [29360128,   37748736)  hH   fp16 [B][1024]
//   [37748736,   41406464)  W2T  fp16 [1786][1024]
//   [41406464,   41938944)  W1T  fp16 [1024][260]
//   [46137344,   46268416)  Gh   fp16 [256][256]
//   [46268416,   46399488)  Gl   fp16 [256][256]  (scaled x2048)
//   [46399488,   46400512)  zc   fp32 [256]
//   [46400512,   46531584)  Uh   fp16 [256][256]
//   [46531584,   46662656)  Ul   fp16 [256][256]  (scaled x2048)

#define NUMV 256
#define QP_ITERS 5
#define NO_LD 1792
#define LSCALE 2048.0f
#define INV_LSCALE (1.0f / 2048.0f)

typedef _Float16 f16x4 __attribute__((ext_vector_type(4)));
typedef _Float16 f16x8 __attribute__((ext_vector_type(8)));
typedef float f32x4 __attribute__((ext_vector_type(4)));

// ---------------- compile-time pentadiagonal Cholesky tables ----------------
struct FacT {
  double invd[256];
  double l1[257];
  double l2[258];
  double z[256];
  float  zcf[256];
};

constexpr double csqrt_(double x) {
  double g = (x > 1.0) ? x : 1.0;
  for (int i = 0; i < 64; ++i) g = 0.5 * (g + x / g);
  return g;
}

constexpr FacT make_fac() {
  FacT f{};
  const double T = 0.05, a = 1.0 / (T * T), b2 = a * a;
  double c0[256] = {}, c1[255] = {}, c2[254] = {};
  double dd[256] = {}, l1[256] = {}, l2[256] = {};
  for (int j = 0; j < 256; j++) {
    double cd1 = (j == 0 || j == 255) ? 1.0 : 2.0;
    double cd2 = (j == 0 || j == 255) ? 1.0 : ((j == 1 || j == 254) ? 5.0 : 6.0);
    c0[j] = 3.0 + 2.0 * a * cd1 + 2.0 * b2 * cd2;
  }
  for (int j = 0; j < 255; j++) c1[j] = -2.0 * a + 2.0 * b2 * ((j == 0 || j == 254) ? -2.0 : -4.0);
  for (int j = 0; j < 254; j++) c2[j] = 2.0 * b2;
  dd[0] = csqrt_(c0[0]); l1[0] = 0.0; l2[0] = 0.0;
  l1[1] = c1[0] / dd[0]; l2[1] = 0.0;
  dd[1] = csqrt_(c0[1] - l1[1] * l1[1]);
  for (int j = 2; j < 256; j++) {
    l2[j] = c2[j - 2] / dd[j - 2];
    l1[j] = (c1[j - 1] - l2[j] * l1[j - 1]) / dd[j - 1];
    dd[j] = csqrt_(c0[j] - l1[j] * l1[j] - l2[j] * l2[j]);
  }
  for (int j = 0; j < 256; j++) f.invd[j] = 1.0 / dd[j];
  for (int j = 0; j < 256; j++) f.l1[j] = l1[j];
  f.l1[256] = 0.0;
  for (int j = 0; j < 256; j++) f.l2[j] = l2[j];
  f.l2[256] = 0.0; f.l2[257] = 0.0;
  double w[256] = {}, zz[256] = {};
  w[0] = 1.0 / dd[0];
  w[1] = (-l1[1] * w[0]) / dd[1];
  for (int j = 2; j < 256; j++) w[j] = (-l1[j] * w[j - 1] - l2[j] * w[j - 2]) / dd[j];
  zz[255] = w[255] / dd[255];
  zz[254] = (w[254] - l1[255] * zz[255]) / dd[254];
  for (int j = 253; j >= 0; j--)
    zz[j] = (w[j] - l1[j + 1] * zz[j + 1] - l2[j + 2] * zz[j + 2]) / dd[j];
  for (int j = 0; j < 256; j++) f.z[j] = zz[j];
  for (int j = 0; j < 256; j++) f.zcf[j] = (float)(zz[j] / zz[0]);
  return f;
}

constexpr FacT FAC_HOST = make_fac();
__constant__ FacT FAC = FAC_HOST;

// ---- compile-time U = L^{-1}: quarter (64 columns) per constexpr evaluation ----
struct UQ { float u[64][256]; };

constexpr UQ make_uq(int cbase) {
  UQ q{};
  const double T = 0.05, a = 1.0 / (T * T), b2 = a * a;
  double c0a[256] = {}, c1a[255] = {}, c2a[254] = {};
  double dd[256] = {}, l1[256] = {}, l2[256] = {};
  for (int j = 0; j < 256; j++) {
    double cd1 = (j == 0 || j == 255) ? 1.0 : 2.0;
    double cd2 = (j == 0 || j == 255) ? 1.0 : ((j == 1 || j == 254) ? 5.0 : 6.0);
    c0a[j] = 3.0 + 2.0 * a * cd1 + 2.0 * b2 * cd2;
  }
  for (int j = 0; j < 255; j++) c1a[j] = -2.0 * a + 2.0 * b2 * ((j == 0 || j == 254) ? -2.0 : -4.0);
  for (int j = 0; j < 254; j++) c2a[j] = 2.0 * b2;
  dd[0] = csqrt_(c0a[0]); l1[0] = 0.0; l2[0] = 0.0;
  l1[1] = c1a[0] / dd[0]; l2[1] = 0.0;
  dd[1] = csqrt_(c0a[1] - l1[1] * l1[1]);
  for (int j = 2; j < 256; j++) {
    l2[j] = c2a[j - 2] / dd[j - 2];
    l1[j] = (c1a[j - 1] - l2[j] * l1[j - 1]) / dd[j - 1];
    dd[j] = csqrt_(c0a[j] - l1[j] * l1[j] - l2[j] * l2[j]);
  }
  for (int c = cbase; c < cbase + 64; ++c) {
    double w1 = 0.0, w2 = 0.0;
    for (int j = c; j < 256; ++j) {
      const double rhs = (j == c) ? 1.0 : 0.0;
      const double wj = (rhs - l1[j] * w1 - l2[j] * w2) / dd[j];
      q.u[c - cbase][j] = (float)wj;
      w2 = w1; w1 = wj;
    }
  }
  return q;
}

constexpr UQ UQ0_H = make_uq(0);
constexpr UQ UQ1_H = make_uq(64);
constexpr UQ UQ2_H = make_uq(128);
constexpr UQ UQ3_H = make_uq(192);
__constant__ UQ UFQ0 = UQ0_H;
__constant__ UQ UFQ1 = UQ1_H;
__constant__ UQ UFQ2 = UQ2_H;
__constant__ UQ UFQ3 = UQ3_H;

// ---- split compile-time U into scaled split-fp16 Uh/Ul; write zc ----
__global__ __launch_bounds__(256) void split_u(
    _Float16* __restrict__ Uh, _Float16* __restrict__ Ul, float* __restrict__ zc)
{
  const int c = blockIdx.x, j = threadIdx.x;
  float wf;
  if (c < 64)       wf = UFQ0.u[c][j];
  else if (c < 128) wf = UFQ1.u[c - 64][j];
  else if (c < 192) wf = UFQ2.u[c - 128][j];
  else              wf = UFQ3.u[c - 192][j];
  const _Float16 h = (_Float16)wf;
  Uh[(size_t)c * 256 + j] = h;
  Ul[(size_t)c * 256 + j] = (_Float16)((wf - (float)h) * LSCALE);
  if (c == 0) zc[j] = FAC.zcf[j];
}

// ---- G = UT * UT^T - z z^T/z0 via split-fp16 MFMA; output re-split to Gh/Gl ----
__global__ __launch_bounds__(64) void gemm_g(
    const _Float16* __restrict__ Uh, const _Float16* __restrict__ Ul,
    _Float16* __restrict__ Gh, _Float16* __restrict__ Gl)
{
  const int lane = threadIdx.x;
  const int lr = lane & 15, lg = lane >> 4;
  const int m0 = blockIdx.x * 16, n0 = blockIdx.y * 32;
  f32x4 accH[2], accL[2];
#pragma unroll
  for (int nf = 0; nf < 2; nf++) { accH[nf] = (f32x4)0.0f; accL[nf] = (f32x4)0.0f; }
  const size_t arow = (size_t)(m0 + lr) * 256 + lg * 8;
#pragma unroll 2
  for (int k0 = 0; k0 < 256; k0 += 32) {
    const f16x8 ah = *reinterpret_cast<const f16x8*>(&Uh[arow + k0]);
    const f16x8 al = *reinterpret_cast<const f16x8*>(&Ul[arow + k0]);
#pragma unroll
    for (int nf = 0; nf < 2; nf++) {
      const size_t bidx = (size_t)(n0 + nf * 16 + lr) * 256 + k0 + lg * 8;
      const f16x8 bh = *reinterpret_cast<const f16x8*>(&Uh[bidx]);
      const f16x8 bl = *reinterpret_cast<const f16x8*>(&Ul[bidx]);
      accH[nf] = __builtin_amdgcn_mfma_f32_16x16x32_f16(ah, bh, accH[nf], 0, 0, 0);
      accL[nf] = __builtin_amdgcn_mfma_f32_16x16x32_f16(ah, bl, accL[nf], 0, 0, 0);
      accL[nf] = __builtin_amdgcn_mfma_f32_16x16x32_f16(al, bh, accL[nf], 0, 0, 0);
    }
  }
  const int row0 = m0 + lg * 4;
#pragma unroll
  for (int nf = 0; nf < 2; nf++) {
    const int col = n0 + nf * 16 + lr;
    const double zcd = FAC.z[col] / FAC.z[0];
#pragma unroll
    for (int r = 0; r < 4; r++) {
      const int row = row0 + r;
      const float g = accH[nf][r] + accL[nf][r] * INV_LSCALE
                    - (float)(FAC.z[row] * zcd);
      const _Float16 gh = (_Float16)g;
      Gh[(size_t)row * 256 + col] = gh;
      Gl[(size_t)row * 256 + col] = (_Float16)((g - (float)gh) * LSCALE);
    }
  }
}

// ---------------- transpose + fp32->fp16 convert: in [K][N] -> out [N][K] ----------------
__global__ __launch_bounds__(256) void transpose_cvt(
    const float* __restrict__ in, _Float16* __restrict__ out, int K, int N)
{
  __shared__ float t[32][33];
  const int bk = blockIdx.x * 32, bn = blockIdx.y * 32;
  const int x = threadIdx.x, y = threadIdx.y;
  for (int yy = y; yy < 32; yy += 8) {
    const int k = bk + yy, n = bn + x;
    t[yy][x] = (k < K && n < N) ? in[(size_t)k * N + n] : 0.f;
  }
  __syncthreads();
  for (int yy = y; yy < 32; yy += 8) {
    const int n = bn + yy, k = bk + x;
    if (n < N && k < K) out[(size_t)n * K + k] = (_Float16)t[x][yy];
  }
}

// ---------------- MFMA GEMM (BK=32, handles fp32 A + K tails): GEMM1 ----------------
template<bool A_FP32, bool OUT_H16>
__global__ __launch_bounds__(256) void mfma_gemm(
    const void* __restrict__ Av, const _Float16* __restrict__ Bt,
    const float* __restrict__ bias, void* __restrict__ Cv,
    int M, int Nv, int K, int lda, int ldk, int ldc)
{
  __shared__ _Float16 At[128][40];
  __shared__ _Float16 Bs[128][40];
  const int tid = threadIdx.x;
  const int lane = tid & 63, wid = tid >> 6;
  const int wr = wid >> 1, wc = wid & 1;
  const int lrow = lane & 15, lb = lane >> 4;
  const int m0 = blockIdx.x * 128, n0 = blockIdx.y * 128;
  const int srow = tid >> 1, skh = (tid & 1) * 16;

  f32x4 acc[4][4];
#pragma unroll
  for (int i = 0; i < 4; i++)
#pragma unroll
    for (int j = 0; j < 4; j++) acc[i][j] = (f32x4)0.0f;

  const int nsteps = (K + 31) / 32;
  for (int t = 0; t < nsteps; ++t) {
    const int k0 = t * 32;
    if (A_FP32) {
      const float* A = (const float*)Av;
#pragma unroll
      for (int i = 0; i < 4; i++) {
        const int k = k0 + skh + i * 4;
        f16x4 hv = {};
        if (k + 4 <= K) {
          const float4 v = *reinterpret_cast<const float4*>(&A[(size_t)(m0 + srow) * lda + k]);
          hv[0] = (_Float16)v.x; hv[1] = (_Float16)v.y;
          hv[2] = (_Float16)v.z; hv[3] = (_Float16)v.w;
        } else if (k < K) {
          for (int e = 0; e < 4; e++)
            if (k + e < K) hv[e] = (_Float16)A[(size_t)(m0 + srow) * lda + k + e];
        }
        *reinterpret_cast<f16x4*>(&At[srow][skh + i * 4]) = hv;
      }
    } else {
      const _Float16* A = (const _Float16*)Av;
#pragma unroll
      for (int i = 0; i < 4; i++) {
        const int k = k0 + skh + i * 4;
        f16x4 hv = {};
        if (k + 4 <= K) hv = *reinterpret_cast<const f16x4*>(&A[(size_t)(m0 + srow) * lda + k]);
        *reinterpret_cast<f16x4*>(&At[srow][skh + i * 4]) = hv;
      }
    }
    {
      const int n = n0 + srow;
#pragma unroll
      for (int i = 0; i < 4; i++) {
        const int k = k0 + skh + i * 4;
        f16x4 hv = {};
        if (n < Nv && k + 4 <= K)
          hv = *reinterpret_cast<const f16x4*>(&Bt[(size_t)n * ldk + k]);
        *reinterpret_cast<f16x4*>(&Bs[srow][skh + i * 4]) = hv;
      }
    }
    __syncthreads();
    f16x8 af[4], bf[4];
#pragma unroll
    for (int i = 0; i < 4; i++)
      af[i] = *reinterpret_cast<const f16x8*>(&At[wr * 64 + i * 16 + lrow][lb * 8]);
#pragma unroll
    for (int j = 0; j < 4; j++)
      bf[j] = *reinterpret_cast<const f16x8*>(&Bs[wc * 64 + j * 16 + lrow][lb * 8]);
#pragma unroll
    for (int i = 0; i < 4; i++)
#pragma unroll
      for (int j = 0; j < 4; j++)
        acc[i][j] = __builtin_amdgcn_mfma_f32_16x16x32_f16(af[i], bf[j], acc[i][j], 0, 0, 0);
    __syncthreads();
  }
#pragma unroll
  for (int i = 0; i < 4; i++) {
#pragma unroll
    for (int j = 0; j < 4; j++) {
      const int gcol = n0 + wc * 64 + j * 16 + lrow;
      if (gcol < Nv) {
        const float bv = bias[gcol];
#pragma unroll
        for (int r = 0; r < 4; r++) {
          const int grow = m0 + wr * 64 + i * 16 + lb * 4 + r;
          float v = acc[i][j][r] + bv;
          if (OUT_H16) {
            v = fmaxf(v, 0.f);
            ((_Float16*)Cv)[(size_t)grow * ldc + gcol] = (_Float16)v;
          } else {
            ((float*)Cv)[(size_t)grow * ldc + gcol] = v;
          }
        }
      }
    }
  }
}

// ---------------- MFMA GEMM BK=64 (fp16 A, K%64==0, fp32 out): GEMM2 ----------------
__global__ __launch_bounds__(256) void mfma_gemm64(
    const _Float16* __restrict__ A, const _Float16* __restrict__ Bt,
    const float* __restrict__ bias, float* __restrict__ C,
    int M, int Nv, int K, int lda, int ldk, int ldc)
{
  __shared__ _Float16 At[128][72];
  __shared__ _Float16 Bs[128][72];
  const int tid = threadIdx.x;
  const int lane = tid & 63, wid = tid >> 6;
  const int wr = wid >> 1, wc = wid & 1;
  const int lrow = lane & 15, lb = lane >> 4;
  const int m0 = blockIdx.x * 128, n0 = blockIdx.y * 128;
  const int srow = tid >> 1, sh = (tid & 1) * 32;

  f32x4 acc[4][4];
#pragma unroll
  for (int i = 0; i < 4; i++)
#pragma unroll
    for (int j = 0; j < 4; j++) acc[i][j] = (f32x4)0.0f;

  const int nsteps = K >> 6;
  for (int t = 0; t < nsteps; ++t) {
    const int k0 = t * 64;
    const _Float16* asrc = &A[(size_t)(m0 + srow) * lda + k0 + sh];
#pragma unroll
    for (int i = 0; i < 4; i++)
      *reinterpret_cast<f16x8*>(&At[srow][sh + i * 8]) =
          *reinterpret_cast<const f16x8*>(asrc + i * 8);
    {
      const int n = n0 + srow;
      const _Float16* bsrc = &Bt[(size_t)n * ldk + k0 + sh];
#pragma unroll
      for (int i = 0; i < 4; i++) {
        f16x8 hv = {};
        if (n < Nv) hv = *reinterpret_cast<const f16x8*>(bsrc + i * 8);
        *reinterpret_cast<f16x8*>(&Bs[srow][sh + i * 8]) = hv;
      }
    }
    __syncthreads();
#pragma unroll
    for (int h = 0; h < 2; h++) {
      f16x8 af[4], bf[4];
#pragma unroll
      for (int i = 0; i < 4; i++)
        af[i] = *reinterpret_cast<const f16x8*>(&At[wr * 64 + i * 16 + lrow][h * 32 + lb * 8]);
#pragma unroll
      for (int j = 0; j < 4; j++)
        bf[j] = *reinterpret_cast<const f16x8*>(&Bs[wc * 64 + j * 16 + lrow][h * 32 + lb * 8]);
#pragma unroll
      for (int i = 0; i < 4; i++)
#pragma unroll
        for (int j = 0; j < 4; j++)
          acc[i][j] = __builtin_amdgcn_mfma_f32_16x16x32_f16(af[i], bf[j], acc[i][j], 0, 0, 0);
    }
    __syncthreads();
  }
#pragma unroll
  for (int i = 0; i < 4; i++) {
#pragma unroll
    for (int j = 0; j < 4; j++) {
      const int gcol = n0 + wc * 64 + j * 16 + lrow;
      if (gcol < Nv) {
        const float bv = bias[gcol];
#pragma unroll
        for (int r = 0; r < 4; r++) {
          const int grow = m0 + wr * 64 + i * 16 + lb * 4 + r;
          C[(size_t)grow * ldc + gcol] = acc[i][j][r] + bv;
        }
      }
    }
  }
}

// ---- ALL 5 QP iterations in one kernel (init_v fused). Block = 16 rows,
// 1024 threads (16 waves). Wave w = 16-col MFMA slice; FULL G hoist (64 VGPRs);
// 32KB LDS pad forces 1 block/CU -> allocator budget 128 VGPRs -> no spill.
// update thread = (j = tid&255, half = tid>>8) x 4 rows. 2 barriers/iter.
__global__ __launch_bounds__(1024) void qp_solve5(
    const _Float16* __restrict__ Gh, const _Float16* __restrict__ Gl,
    const float* __restrict__ beq, const float* __restrict__ zc,
    const float* __restrict__ NO, const float* __restrict__ ss,
    const float* __restrict__ p_smax, const float* __restrict__ p_smin,
    const float* __restrict__ p_sdmax, const float* __restrict__ p_sdmin,
    const float* __restrict__ p_sddmax, const float* __restrict__ p_sddmin,
    float* __restrict__ out, int B)
{
  __shared__ float xsA[16][264], xsB[16][264];
  __shared__ _Float16 vhs[16][264], vls[16][264];
  __shared__ float zcs[256], beqs[16];
  __shared__ float red[16][4][3];
  __shared__ float occ_pad[8192];   // 32KB: forces 1 block/CU -> 128-VGPR budget
  const int tid = threadIdx.x;
  const int wave = tid >> 6, lane = tid & 63;
  const int lr = lane & 15, lg = lane >> 4;
  const int m0 = blockIdx.x * 16;
  const int n0 = wave * 16;
  const int j = tid & 255, half = tid >> 8;    // half in 0..3

  // runtime-opaque keepalive for the pad (B is a kernel arg; never <0)
  if (B < 0) { occ_pad[tid & 8191] = beq[0]; out[0] = occ_pad[(tid + 1) & 8191]; }

  const float smax = *p_smax, smin = *p_smin;
  const float sdmax = *p_sdmax, sdmin = *p_sdmin;
  const float sddmax = *p_sddmax, sddmin = *p_sddmin;
  const float K0 = smax + smin, K1 = sdmax + sdmin, K2 = sddmax + sddmin;
  const float invT = 20.f, invT2 = 400.f;
  const bool h1 = j < 255, h2 = j < 254;

  // ---- FULL G hoist for this wave's 16-col slice (64 VGPRs) ----
  f16x8 gh_r[8], gl_r[8];
#pragma unroll
  for (int kk = 0; kk < 8; kk++) {
    const size_t bidx = (size_t)(n0 + lr) * 256 + kk * 32 + lg * 8;
    gh_r[kk] = *reinterpret_cast<const f16x8*>(&Gh[bidx]);
    gl_r[kk] = *reinterpret_cast<const f16x8*>(&Gl[bidx]);
  }

  // ---- per-thread persistent state + FUSED init_v (round-8-validated formula) ----
  float lamr[4], ssv[4];
#pragma unroll
  for (int rr = 0; rr < 4; rr++) {
    const int rl = half * 4 + rr;
    const int gr = m0 + rl;
    const float* no = NO + (size_t)gr * NO_LD;
    ssv[rr] = ss[(size_t)gr * NUMV + j];
    lamr[rr] = no[j];
    const float D0 = K0 - fmaxf(0.f, no[256 + j]) + fmaxf(0.f, no[512 + j]);
    const float D1j = h1 ? (K1 - fmaxf(0.f, no[768 + j]) + fmaxf(0.f, no[1023 + j])) : 0.f;
    const float D1m = (j >= 1) ? (K1 - fmaxf(0.f, no[768 + j - 1]) + fmaxf(0.f, no[1023 + j - 1])) : 0.f;
    const float D2j = h2 ? (K2 - fmaxf(0.f, no[1278 + j]) + fmaxf(0.f, no[1532 + j])) : 0.f;
    const float D2m1 = (j >= 1 && h1) ? (K2 - fmaxf(0.f, no[1278 + j - 1]) + fmaxf(0.f, no[1532 + j - 1])) : 0.f;
    const float D2m2 = (j >= 2) ? (K2 - fmaxf(0.f, no[1278 + j - 2]) + fmaxf(0.f, no[1532 + j - 2])) : 0.f;
    const float vn = lamr[rr] + ssv[rr]
                   + D0 + (D1m - D1j) * invT + (D2m2 - 2.f * D2m1 + D2j) * invT2;
    const _Float16 vh16 = (_Float16)vn;
    vhs[rl][j] = vh16;
    vls[rl][j] = (_Float16)((vn - (float)vh16) * LSCALE);
  }
  if (tid < 256) zcs[tid] = zc[tid];
  if (tid < 16) {
    beqs[tid] = beq[m0 + tid];
    xsA[tid][0] = 0.f; xsA[tid][1] = 0.f; xsA[tid][258] = 0.f; xsA[tid][259] = 0.f;
    xsB[tid][0] = 0.f; xsB[tid][1] = 0.f; xsB[tid][258] = 0.f; xsB[tid][259] = 0.f;
  }
  float accP = 0.f, accF = 0.f;

  const size_t primOff = (size_t)B * NUMV;
  const size_t fpOff = primOff + (size_t)QP_ITERS * B;
  const size_t accPOff = fpOff + (size_t)QP_ITERS * B;
  const size_t accFOff = accPOff + (size_t)B;

  float (*xc)[264] = xsA;
  float (*xp)[264] = xsB;

  __syncthreads();    // staged vhs/vls/zcs/beqs ready

  for (int it = 0; it < QP_ITERS; ++it) {
    // ---- Phase 1: MFMA solve (validated split-fp16 path; V in LDS, G in regs) ----
    f32x4 accH = (f32x4)0.0f, accL = (f32x4)0.0f;
#pragma unroll
    for (int kk = 0; kk < 8; kk++) {
      const f16x8 ah = *reinterpret_cast<const f16x8*>(&vhs[lr][kk * 32 + lg * 8]);
      const f16x8 al = *reinterpret_cast<const f16x8*>(&vls[lr][kk * 32 + lg * 8]);
      accH = __builtin_amdgcn_mfma_f32_16x16x32_f16(ah, gh_r[kk], accH, 0, 0, 0);
      accL = __builtin_amdgcn_mfma_f32_16x16x32_f16(ah, gl_r[kk], accL, 0, 0, 0);
      accL = __builtin_amdgcn_mfma_f32_16x16x32_f16(al, gh_r[kk], accL, 0, 0, 0);
    }
    {
      const int r0l = lg * 4;
      const int col = n0 + lr;
      const float zv = zcs[col];
#pragma unroll
      for (int r = 0; r < 4; r++)
        xc[r0l + r][col + 2] = accH[r] + accL[r] * INV_LSCALE + beqs[r0l + r] * zv;
    }
    __syncthreads();    // x ready; previous red consumed

    // ---- Phase 2: update (validated local-recompute stencils), 4 rows/thread ----
#pragma unroll
    for (int rr = 0; rr < 4; rr++) {
      const int rl = half * 4 + rr;
      const int gr = m0 + rl;
      const float xm2 = xc[rl][j];
      const float xm1 = xc[rl][j + 1];
      const float x0  = xc[rl][j + 2];
      const float x1  = xc[rl][j + 3];
      const float x2  = xc[rl][j + 4];

      const float vj = (x1 - x0) * invT;
      const float aj = (x2 - 2.f * x1 + x0) * invT2;
      const float vm1 = (x0 - xm1) * invT;
      const float am1 = (x1 - 2.f * x0 + xm1) * invT2;
      const float am2 = (x0 - 2.f * xm1 + xm2) * invT2;

      const float rv0a = fmaxf(0.f, x0 - smax), rv0b = fmaxf(0.f, smin - x0);
      const float E0 = rv0a - rv0b;
      float rv1a = 0.f, rv1b = 0.f, rv2a = 0.f, rv2b = 0.f, E1 = 0.f, E2 = 0.f;
      if (h1) { rv1a = fmaxf(0.f, vj - sdmax); rv1b = fmaxf(0.f, sdmin - vj); E1 = rv1a - rv1b; }
      if (h2) { rv2a = fmaxf(0.f, aj - sddmax); rv2b = fmaxf(0.f, sddmin - aj); E2 = rv2a - rv2b; }
      float res2 = rv0a * rv0a + rv0b * rv0b + rv1a * rv1a + rv1b * rv1b
                 + rv2a * rv2a + rv2b * rv2b;

      const float E1m = (j >= 1) ? (fmaxf(0.f, vm1 - sdmax) - fmaxf(0.f, sdmin - vm1)) : 0.f;
      const float E2m1 = (j >= 1 && h1) ? (fmaxf(0.f, am1 - sddmax) - fmaxf(0.f, sddmin - am1)) : 0.f;
      const float E2m2 = (j >= 2) ? (fmaxf(0.f, am2 - sddmax) - fmaxf(0.f, sddmin - am2)) : 0.f;

      const float dl = E0 + (E1m - E1) * invT + (E2m2 - 2.f * E2m1 + E2) * invT2;
      const float lnew = lamr[rr] - dl;
      const float fpl2 = dl * dl;
      lamr[rr] = lnew;

      const float sn0a = fmaxf(0.f, smax - x0), sn0b = fmaxf(0.f, x0 - smin);
      float sn1a = 0.f, sn1b = 0.f, sn2a = 0.f, sn2b = 0.f;
      if (h1) { sn1a = fmaxf(0.f, sdmax - vj); sn1b = fmaxf(0.f, vj - sdmin); }
      if (h2) { sn2a = fmaxf(0.f, sddmax - aj); sn2b = fmaxf(0.f, aj - sddmin); }

      float sp0a, sp0b, sp1a = 0.f, sp1b = 0.f, sp2a = 0.f, sp2b = 0.f;
      if (it == 0) {
        const float* no = NO + (size_t)gr * NO_LD;
        sp0a = fmaxf(0.f, no[256 + j]); sp0b = fmaxf(0.f, no[512 + j]);
        if (h1) { sp1a = fmaxf(0.f, no[768 + j]); sp1b = fmaxf(0.f, no[1023 + j]); }
        if (h2) { sp2a = fmaxf(0.f, no[1278 + j]); sp2b = fmaxf(0.f, no[1532 + j]); }
      } else {
        const float p0 = xp[rl][j + 2], p1 = xp[rl][j + 3], p2 = xp[rl][j + 4];
        const float vp = (p1 - p0) * invT;
        const float ap = (p2 - 2.f * p1 + p0) * invT2;
        sp0a = fmaxf(0.f, smax - p0); sp0b = fmaxf(0.f, p0 - smin);
        if (h1) { sp1a = fmaxf(0.f, sdmax - vp); sp1b = fmaxf(0.f, vp - sdmin); }
        if (h2) { sp2a = fmaxf(0.f, sddmax - ap); sp2b = fmaxf(0.f, ap - sddmin); }
      }
      const float d0a = sp0a - sn0a, d0b = sp0b - sn0b;
      const float d1a = sp1a - sn1a, d1b = sp1b - sn1b;
      const float d2a = sp2a - sn2a, d2b = sp2b - sn2b;
      float fps2 = d0a * d0a + d0b * d0b + d1a * d1a + d1b * d1b
                 + d2a * d2a + d2b * d2b;

      const float D0 = fminf(smax, x0) + fmaxf(smin, x0);
      const float D1 = h1 ? (fminf(sdmax, vj) + fmaxf(sdmin, vj)) : 0.f;
      const float D2 = h2 ? (fminf(sddmax, aj) + fmaxf(sddmin, aj)) : 0.f;
      const float D1m = (j >= 1) ? (fminf(sdmax, vm1) + fmaxf(sdmin, vm1)) : 0.f;
      const float D2m1 = (j >= 1 && h1) ? (fminf(sddmax, am1) + fmaxf(sddmin, am1)) : 0.f;
      const float D2m2 = (j >= 2) ? (fminf(sddmax, am2) + fmaxf(sddmin, am2)) : 0.f;

      if (it < QP_ITERS - 1) {
        const float vn = lnew + ssv[rr]
                       + D0 + (D1m - D1) * invT + (D2m2 - 2.f * D2m1 + D2) * invT2;
        const _Float16 vh16 = (_Float16)vn;
        vhs[rl][j] = vh16;
        vls[rl][j] = (_Float16)((vn - (float)vh16) * LSCALE);
      } else {
        out[(size_t)gr * NUMV + j] = x0;
      }

      float a = res2, b = fps2, c = fpl2;
      for (int o = 32; o > 0; o >>= 1) {
        a += __shfl_down(a, o);
        b += __shfl_down(b, o);
        c += __shfl_down(c, o);
      }
      if (lane == 0) { red[wave][rr][0] = a; red[wave][rr][1] = b; red[wave][rr][2] = c; }
    }
    __syncthreads();    // red + vhs/vls ready; xp consumed

    if (tid < 16) {
      const int rl = tid, hf = rl >> 2, rr = rl & 3;
      const int w0 = hf * 4;
      const float r2 = red[w0][rr][0] + red[w0 + 1][rr][0] + red[w0 + 2][rr][0] + red[w0 + 3][rr][0];
      const float s2 = red[w0][rr][1] + red[w0 + 1][rr][1] + red[w0 + 2][rr][1] + red[w0 + 3][rr][1];
      const float l2 = red[w0][rr][2] + red[w0 + 1][rr][2] + red[w0 + 2][rr][2] + red[w0 + 3][rr][2];
      const float pr = sqrtf(r2);
      const float fp = sqrtf(s2) + sqrtf(l2);
      out[primOff + (size_t)it * B + m0 + rl] = pr;
      out[fpOff + (size_t)it * B + m0 + rl] = fp;
      accP += pr; accF += fp;
    }
    // swap x buffers
    float (*t)[264] = xc; xc = xp; xp = t;
  }
  if (tid < 16) {
    out[accPOff + m0 + tid] = accP * (1.f / QP_ITERS);
    out[accFOff + m0 + tid] = accF * (1.f / QP_ITERS);
  }
}

extern "C" void kernel_launch(void* const* d_in, const int* in_sizes, int n_in,
                              void* d_out, int out_size, void* d_ws, size_t ws_size,
                              hipStream_t stream)
{
  const float* inp = (const float*)d_in[0];       // [B][260]
  const float* sinit = (const float*)d_in[1];     // [B][1]
  const float* ssamp = (const float*)d_in[2];     // [B][256]
  const float* p_smax = (const float*)d_in[3];
  const float* p_smin = (const float*)d_in[4];
  const float* p_sdmax = (const float*)d_in[5];
  const float* p_sdmin = (const float*)d_in[6];
  const float* p_sddmax = (const float*)d_in[7];
  const float* p_sddmin = (const float*)d_in[8];
  const float* W1 = (const float*)d_in[11];       // [260][1024]
  const float* b1 = (const float*)d_in[12];       // [1024]
  const float* W2 = (const float*)d_in[13];       // [1024][1786]
  const float* b2 = (const float*)d_in[14];       // [1786]
  float* out = (float*)d_out;

  const int B = in_sizes[1];                      // 4096
  const int IND = in_sizes[9];                    // 260
  const int H = in_sizes[12];                     // 1024
  const int OUTN = in_sizes[14];                  // 1786

  char* ws = (char*)d_ws;
  float* NO = (float*)ws;                                      // [B][1792] fp32
  char* p = ws + (size_t)B * NO_LD * 4;                        // 29,360,128
  _Float16* hH = (_Float16*)p;                                 // [B][1024] fp16
  char* q = p + (size_t)B * H * 2;                             // 37,748,736
  _Float16* W2T = (_Float16*)q;                                // [1786][1024] fp16
  char* q2 = q + (size_t)OUTN * H * 2;                         // 41,406,464
  _Float16* W1T = (_Float16*)q2;                               // [1024][260] fp16
  char* r4 = ws + 46137344;                                    // 46,137,344
  _Float16* Gh = (_Float16*)r4;                                // [256][256] fp16
  _Float16* Gl = (_Float16*)(r4 + 131072);                     // [256][256] fp16 (x2048)
  float* zc = (float*)(r4 + 262144);                           // [256] fp32
  _Float16* Uh = (_Float16*)(r4 + 263168);                     // [256][256] fp16 (U^T)
  _Float16* Ul = (_Float16*)(r4 + 263168 + 131072);            // [256][256] fp16 (x2048)

  split_u<<<256, 256, 0, stream>>>(Uh, Ul, zc);
  {
    dim3 g(16, 8);
    gemm_g<<<g, 64, 0, stream>>>(Uh, Ul, Gh, Gl);
  }
  {
    dim3 g((IND + 31) / 32, (H + 31) / 32), blk(32, 8);
    transpose_cvt<<<g, blk, 0, stream>>>(W1, W1T, IND, H);
  }
  {
    dim3 g((H + 31) / 32, (OUTN + 31) / 32), blk(32, 8);
    transpose_cvt<<<g, blk, 0, stream>>>(W2, W2T, H, OUTN);
  }
  {
    dim3 g(B / 128, H / 128);
    mfma_gemm<true, true><<<g, 256, 0, stream>>>(inp, W1T, b1, hH, B, H, IND, IND, IND, H);
  }
  {
    dim3 g(B / 128, (OUTN + 127) / 128);
    mfma_gemm64<<<g, 256, 0, stream>>>(hH, W2T, b2, NO, B, OUTN, H, H, H, NO_LD);
  }
  qp_solve5<<<B / 16, 1024, 0, stream>>>(Gh, Gl, sinit, zc, NO, ssamp,
                                         p_smax, p_smin, p_sdmax, p_sdmin,
                                         p_sddmax, p_sddmin, out, B);
}

// Round 27
// 142.669 us; speedup vs baseline: 1.0766x; 1.0766x over previous
//
#include <hip/hip_runtime.h>
#include <cstddef>

// learned_qp_solver: B=4096, NUM=256, NC=1530, IND=260, H=1024, OUT=1786, 5 iters.
//
//   KKT solve closed form:  x = G v + (b_eq/z0) z,  G = C^{-1} - z z^T / z0 (symmetric)
//   MLP on matrix cores: v_mfma_f32_16x16x32_f16 (BK=32 GEMM1 / BK=64 GEMM2).
//   Solve: scaled split-fp16 (Gl,Vl x2048 dodge fp16 denormal flush in MFMA).
//   G build: U = L^{-1} at COMPILE TIME (constexpr quarters); gemm_g on MFMA.
//   qp_solve5: round-25 exact (measured best 152.28us): init_v fused, 16 rows,
//   1024 threads, half G hoist (Gh regs / Gl L2). Rounds 19-26 lesson: the
//   64-VGPR pin is immovable (launch_bounds/waves_per_eu/AGPR-asm/LDS-pad all
//   failed); spilled-half-hoist is the empirical optimum of that structure.
//   Round-27: GEMM2 (mfma_gemm64) staging rewritten with global_load_lds
//   width=16 (guide Common-mistake #1; +35-67% measured on this structure) +
//   both-sides XOR swizzle (linear LDS dest mandated by gload_lds; source
//   k-offset pre-swizzled 8*((l&7)^(l>>3)), fragment reads XOR (row&7)<<3 ->
//   2-way conflicts only).
//
// ws layout (bytes), ~46.7 MB:
//   [0,          29360128)  NO   fp32 [B][1792]
//   [29360128,   37748736)  hH   fp16 [B][1024]
//   [37748736,   41406464)  W2T  fp16 [1786][1024]
//   [41406464,   41938944)  W1T  fp16 [1024][260]
//   [46137344,   46268416)  Gh   fp16 [256][256]
//   [46268416,   46399488)  Gl   fp16 [256][256]  (scaled x2048)
//   [46399488,   46400512)  zc   fp32 [256]
//   [46400512,   46531584)  Uh   fp16 [256][256]
//   [46531584,   46662656)  Ul   fp16 [256][256]  (scaled x2048)

#define NUMV 256
#define QP_ITERS 5
#define NO_LD 1792
#define LSCALE 2048.0f
#define INV_LSCALE (1.0f / 2048.0f)

typedef _Float16 f16x4 __attribute__((ext_vector_type(4)));
typedef _Float16 f16x8 __attribute__((ext_vector_type(8)));
typedef float f32x4 __attribute__((ext_vector_type(4)));

// ---------------- compile-time pentadiagonal Cholesky tables ----------------
struct FacT {
  double invd[256];
  double l1[257];
  double l2[258];
  double z[256];
  float  zcf[256];
};

constexpr double csqrt_(double x) {
  double g = (x > 1.0) ? x : 1.0;
  for (int i = 0; i < 64; ++i) g = 0.5 * (g + x / g);
  return g;
}

constexpr FacT make_fac() {
  FacT f{};
  const double T = 0.05, a = 1.0 / (T * T), b2 = a * a;
  double c0[256] = {}, c1[255] = {}, c2[254] = {};
  double dd[256] = {}, l1[256] = {}, l2[256] = {};
  for (int j = 0; j < 256; j++) {
    double cd1 = (j == 0 || j == 255) ? 1.0 : 2.0;
    double cd2 = (j == 0 || j == 255) ? 1.0 : ((j == 1 || j == 254) ? 5.0 : 6.0);
    c0[j] = 3.0 + 2.0 * a * cd1 + 2.0 * b2 * cd2;
  }
  for (int j = 0; j < 255; j++) c1[j] = -2.0 * a + 2.0 * b2 * ((j == 0 || j == 254) ? -2.0 : -4.0);
  for (int j = 0; j < 254; j++) c2[j] = 2.0 * b2;
  dd[0] = csqrt_(c0[0]); l1[0] = 0.0; l2[0] = 0.0;
  l1[1] = c1[0] / dd[0]; l2[1] = 0.0;
  dd[1] = csqrt_(c0[1] - l1[1] * l1[1]);
  for (int j = 2; j < 256; j++) {
    l2[j] = c2[j - 2] / dd[j - 2];
    l1[j] = (c1[j - 1] - l2[j] * l1[j - 1]) / dd[j - 1];
    dd[j] = csqrt_(c0[j] - l1[j] * l1[j] - l2[j] * l2[j]);
  }
  for (int j = 0; j < 256; j++) f.invd[j] = 1.0 / dd[j];
  for (int j = 0; j < 256; j++) f.l1[j] = l1[j];
  f.l1[256] = 0.0;
  for (int j = 0; j < 256; j++) f.l2[j] = l2[j];
  f.l2[256] = 0.0; f.l2[257] = 0.0;
  double w[256] = {}, zz[256] = {};
  w[0] = 1.0 / dd[0];
  w[1] = (-l1[1] * w[0]) / dd[1];
  for (int j = 2; j < 256; j++) w[j] = (-l1[j] * w[j - 1] - l2[j] * w[j - 2]) / dd[j];
  zz[255] = w[255] / dd[255];
  zz[254] = (w[254] - l1[255] * zz[255]) / dd[254];
  for (int j = 253; j >= 0; j--)
    zz[j] = (w[j] - l1[j + 1] * zz[j + 1] - l2[j + 2] * zz[j + 2]) / dd[j];
  for (int j = 0; j < 256; j++) f.z[j] = zz[j];
  for (int j = 0; j < 256; j++) f.zcf[j] = (float)(zz[j] / zz[0]);
  return f;
}

constexpr FacT FAC_HOST = make_fac();
__constant__ FacT FAC = FAC_HOST;

// ---- compile-time U = L^{-1}: quarter (64 columns) per constexpr evaluation ----
struct UQ { float u[64][256]; };

constexpr UQ make_uq(int cbase) {
  UQ q{};
  const double T = 0.05, a = 1.0 / (T * T), b2 = a * a;
  double c0a[256] = {}, c1a[255] = {}, c2a[254] = {};
  double dd[256] = {}, l1[256] = {}, l2[256] = {};
  for (int j = 0; j < 256; j++) {
    double cd1 = (j == 0 || j == 255) ? 1.0 : 2.0;
    double cd2 = (j == 0 || j == 255) ? 1.0 : ((j == 1 || j == 254) ? 5.0 : 6.0);
    c0a[j] = 3.0 + 2.0 * a * cd1 + 2.0 * b2 * cd2;
  }
  for (int j = 0; j < 255; j++) c1a[j] = -2.0 * a + 2.0 * b2 * ((j == 0 || j == 254) ? -2.0 : -4.0);
  for (int j = 0; j < 254; j++) c2a[j] = 2.0 * b2;
  dd[0] = csqrt_(c0a[0]); l1[0] = 0.0; l2[0] = 0.0;
  l1[1] = c1a[0] / dd[0]; l2[1] = 0.0;
  dd[1] = csqrt_(c0a[1] - l1[1] * l1[1]);
  for (int j = 2; j < 256; j++) {
    l2[j] = c2a[j - 2] / dd[j - 2];
    l1[j] = (c1a[j - 1] - l2[j] * l1[j - 1]) / dd[j - 1];
    dd[j] = csqrt_(c0a[j] - l1[j] * l1[j] - l2[j] * l2[j]);
  }
  for (int c = cbase; c < cbase + 64; ++c) {
    double w1 = 0.0, w2 = 0.0;
    for (int j = c; j < 256; ++j) {
      const double rhs = (j == c) ? 1.0 : 0.0;
      const double wj = (rhs - l1[j] * w1 - l2[j] * w2) / dd[j];
      q.u[c - cbase][j] = (float)wj;
      w2 = w1; w1 = wj;
    }
  }
  return q;
}

constexpr UQ UQ0_H = make_uq(0);
constexpr UQ UQ1_H = make_uq(64);
constexpr UQ UQ2_H = make_uq(128);
constexpr UQ UQ3_H = make_uq(192);
__constant__ UQ UFQ0 = UQ0_H;
__constant__ UQ UFQ1 = UQ1_H;
__constant__ UQ UFQ2 = UQ2_H;
__constant__ UQ UFQ3 = UQ3_H;

// ---- split compile-time U into scaled split-fp16 Uh/Ul; write zc ----
__global__ __launch_bounds__(256) void split_u(
    _Float16* __restrict__ Uh, _Float16* __restrict__ Ul, float* __restrict__ zc)
{
  const int c = blockIdx.x, j = threadIdx.x;
  float wf;
  if (c < 64)       wf = UFQ0.u[c][j];
  else if (c < 128) wf = UFQ1.u[c - 64][j];
  else if (c < 192) wf = UFQ2.u[c - 128][j];
  else              wf = UFQ3.u[c - 192][j];
  const _Float16 h = (_Float16)wf;
  Uh[(size_t)c * 256 + j] = h;
  Ul[(size_t)c * 256 + j] = (_Float16)((wf - (float)h) * LSCALE);
  if (c == 0) zc[j] = FAC.zcf[j];
}

// ---- G = UT * UT^T - z z^T/z0 via split-fp16 MFMA; output re-split to Gh/Gl ----
__global__ __launch_bounds__(64) void gemm_g(
    const _Float16* __restrict__ Uh, const _Float16* __restrict__ Ul,
    _Float16* __restrict__ Gh, _Float16* __restrict__ Gl)
{
  const int lane = threadIdx.x;
  const int lr = lane & 15, lg = lane >> 4;
  const int m0 = blockIdx.x * 16, n0 = blockIdx.y * 32;
  f32x4 accH[2], accL[2];
#pragma unroll
  for (int nf = 0; nf < 2; nf++) { accH[nf] = (f32x4)0.0f; accL[nf] = (f32x4)0.0f; }
  const size_t arow = (size_t)(m0 + lr) * 256 + lg * 8;
#pragma unroll 2
  for (int k0 = 0; k0 < 256; k0 += 32) {
    const f16x8 ah = *reinterpret_cast<const f16x8*>(&Uh[arow + k0]);
    const f16x8 al = *reinterpret_cast<const f16x8*>(&Ul[arow + k0]);
#pragma unroll
    for (int nf = 0; nf < 2; nf++) {
      const size_t bidx = (size_t)(n0 + nf * 16 + lr) * 256 + k0 + lg * 8;
      const f16x8 bh = *reinterpret_cast<const f16x8*>(&Uh[bidx]);
      const f16x8 bl = *reinterpret_cast<const f16x8*>(&Ul[bidx]);
      accH[nf] = __builtin_amdgcn_mfma_f32_16x16x32_f16(ah, bh, accH[nf], 0, 0, 0);
      accL[nf] = __builtin_amdgcn_mfma_f32_16x16x32_f16(ah, bl, accL[nf], 0, 0, 0);
      accL[nf] = __builtin_amdgcn_mfma_f32_16x16x32_f16(al, bh, accL[nf], 0, 0, 0);
    }
  }
  const int row0 = m0 + lg * 4;
#pragma unroll
  for (int nf = 0; nf < 2; nf++) {
    const int col = n0 + nf * 16 + lr;
    const double zcd = FAC.z[col] / FAC.z[0];
#pragma unroll
    for (int r = 0; r < 4; r++) {
      const int row = row0 + r;
      const float g = accH[nf][r] + accL[nf][r] * INV_LSCALE
                    - (float)(FAC.z[row] * zcd);
      const _Float16 gh = (_Float16)g;
      Gh[(size_t)row * 256 + col] = gh;
      Gl[(size_t)row * 256 + col] = (_Float16)((g - (float)gh) * LSCALE);
    }
  }
}

// ---------------- transpose + fp32->fp16 convert: in [K][N] -> out [N][K] ----------------
__global__ __launch_bounds__(256) void transpose_cvt(
    const float* __restrict__ in, _Float16* __restrict__ out, int K, int N)
{
  __shared__ float t[32][33];
  const int bk = blockIdx.x * 32, bn = blockIdx.y * 32;
  const int x = threadIdx.x, y = threadIdx.y;
  for (int yy = y; yy < 32; yy += 8) {
    const int k = bk + yy, n = bn + x;
    t[yy][x] = (k < K && n < N) ? in[(size_t)k * N + n] : 0.f;
  }
  __syncthreads();
  for (int yy = y; yy < 32; yy += 8) {
    const int n = bn + yy, k = bk + x;
    if (n < N && k < K) out[(size_t)n * K + k] = (_Float16)t[x][yy];
  }
}

// ---------------- MFMA GEMM (BK=32, handles fp32 A + K tails): GEMM1 ----------------
template<bool A_FP32, bool OUT_H16>
__global__ __launch_bounds__(256) void mfma_gemm(
    const void* __restrict__ Av, const _Float16* __restrict__ Bt,
    const float* __restrict__ bias, void* __restrict__ Cv,
    int M, int Nv, int K, int lda, int ldk, int ldc)
{
  __shared__ _Float16 At[128][40];
  __shared__ _Float16 Bs[128][40];
  const int tid = threadIdx.x;
  const int lane = tid & 63, wid = tid >> 6;
  const int wr = wid >> 1, wc = wid & 1;
  const int lrow = lane & 15, lb = lane >> 4;
  const int m0 = blockIdx.x * 128, n0 = blockIdx.y * 128;
  const int srow = tid >> 1, skh = (tid & 1) * 16;

  f32x4 acc[4][4];
#pragma unroll
  for (int i = 0; i < 4; i++)
#pragma unroll
    for (int j = 0; j < 4; j++) acc[i][j] = (f32x4)0.0f;

  const int nsteps = (K + 31) / 32;
  for (int t = 0; t < nsteps; ++t) {
    const int k0 = t * 32;
    if (A_FP32) {
      const float* A = (const float*)Av;
#pragma unroll
      for (int i = 0; i < 4; i++) {
        const int k = k0 + skh + i * 4;
        f16x4 hv = {};
        if (k + 4 <= K) {
          const float4 v = *reinterpret_cast<const float4*>(&A[(size_t)(m0 + srow) * lda + k]);
          hv[0] = (_Float16)v.x; hv[1] = (_Float16)v.y;
          hv[2] = (_Float16)v.z; hv[3] = (_Float16)v.w;
        } else if (k < K) {
          for (int e = 0; e < 4; e++)
            if (k + e < K) hv[e] = (_Float16)A[(size_t)(m0 + srow) * lda + k + e];
        }
        *reinterpret_cast<f16x4*>(&At[srow][skh + i * 4]) = hv;
      }
    } else {
      const _Float16* A = (const _Float16*)Av;
#pragma unroll
      for (int i = 0; i < 4; i++) {
        const int k = k0 + skh + i * 4;
        f16x4 hv = {};
        if (k + 4 <= K) hv = *reinterpret_cast<const f16x4*>(&A[(size_t)(m0 + srow) * lda + k]);
        *reinterpret_cast<f16x4*>(&At[srow][skh + i * 4]) = hv;
      }
    }
    {
      const int n = n0 + srow;
#pragma unroll
      for (int i = 0; i < 4; i++) {
        const int k = k0 + skh + i * 4;
        f16x4 hv = {};
        if (n < Nv && k + 4 <= K)
          hv = *reinterpret_cast<const f16x4*>(&Bt[(size_t)n * ldk + k]);
        *reinterpret_cast<f16x4*>(&Bs[srow][skh + i * 4]) = hv;
      }
    }
    __syncthreads();
    f16x8 af[4], bf[4];
#pragma unroll
    for (int i = 0; i < 4; i++)
      af[i] = *reinterpret_cast<const f16x8*>(&At[wr * 64 + i * 16 + lrow][lb * 8]);
#pragma unroll
    for (int j = 0; j < 4; j++)
      bf[j] = *reinterpret_cast<const f16x8*>(&Bs[wc * 64 + j * 16 + lrow][lb * 8]);
#pragma unroll
    for (int i = 0; i < 4; i++)
#pragma unroll
      for (int j = 0; j < 4; j++)
        acc[i][j] = __builtin_amdgcn_mfma_f32_16x16x32_f16(af[i], bf[j], acc[i][j], 0, 0, 0);
    __syncthreads();
  }
#pragma unroll
  for (int i = 0; i < 4; i++) {
#pragma unroll
    for (int j = 0; j < 4; j++) {
      const int gcol = n0 + wc * 64 + j * 16 + lrow;
      if (gcol < Nv) {
        const float bv = bias[gcol];
#pragma unroll
        for (int r = 0; r < 4; r++) {
          const int grow = m0 + wr * 64 + i * 16 + lb * 4 + r;
          float v = acc[i][j][r] + bv;
          if (OUT_H16) {
            v = fmaxf(v, 0.f);
            ((_Float16*)Cv)[(size_t)grow * ldc + gcol] = (_Float16)v;
          } else {
            ((float*)Cv)[(size_t)grow * ldc + gcol] = v;
          }
        }
      }
    }
  }
}

// ---------------- MFMA GEMM BK=64 (fp16 A, K%64==0, M%128==0, fp32 out): GEMM2 ----
// Round-27: global_load_lds width=16 staging (linear LDS dest) + both-sides XOR
// swizzle. Chunk ci (0..15) = 1KB = 8 rows x 64 f16; lane l -> row ci*8+(l>>3),
// k-offset PRE-SWIZZLED 8*((l&7)^(l>>3)) so logical k lives at col k^((row&7)<<3).
// Fragment reads apply the same XOR -> 2-way bank conflicts (free).
// B n-tail (n0+row >= Nv) reads in-bounds garbage; outputs discarded (gcol<Nv).
__global__ __launch_bounds__(256) void mfma_gemm64(
    const _Float16* __restrict__ A, const _Float16* __restrict__ Bt,
    const float* __restrict__ bias, float* __restrict__ C,
    int M, int Nv, int K, int lda, int ldk, int ldc)
{
  __shared__ _Float16 At[128][64];
  __shared__ _Float16 Bs[128][64];
  const int tid = threadIdx.x;
  const int lane = tid & 63, wid = tid >> 6;
  const int wr = wid >> 1, wc = wid & 1;
  const int lrow = lane & 15, lb = lane >> 4;
  const int m0 = blockIdx.x * 128, n0 = blockIdx.y * 128;

  // gload_lds staging geometry (per wave: 4 chunks of 1KB each)
  const int srow8 = lane >> 3;                 // row within chunk (0..7)
  const int kswz = 8 * ((lane & 7) ^ srow8);   // pre-swizzled k offset (f16 units)

  f32x4 acc[4][4];
#pragma unroll
  for (int i = 0; i < 4; i++)
#pragma unroll
    for (int j = 0; j < 4; j++) acc[i][j] = (f32x4)0.0f;

  const int nsteps = K >> 6;
  for (int t = 0; t < nsteps; ++t) {
    const int k0 = t * 64;
#pragma unroll
    for (int c = 0; c < 4; ++c) {
      const int ci = wid * 4 + c;              // chunk 0..15 (wave-uniform)
      const int row = ci * 8 + srow8;
      const _Float16* asrc = &A[(size_t)(m0 + row) * lda + k0 + kswz];
      const _Float16* bsrc = &Bt[(size_t)(n0 + row) * ldk + k0 + kswz];
      __builtin_amdgcn_global_load_lds(
          (const __attribute__((address_space(1))) void*)asrc,
          (__attribute__((address_space(3))) void*)(&At[ci * 8][0]), 16, 0, 0);
      __builtin_amdgcn_global_load_lds(
          (const __attribute__((address_space(1))) void*)bsrc,
          (__attribute__((address_space(3))) void*)(&Bs[ci * 8][0]), 16, 0, 0);
    }
    __syncthreads();
#pragma unroll
    for (int h = 0; h < 2; h++) {
      f16x8 af[4], bf[4];
#pragma unroll
      for (int i = 0; i < 4; i++) {
        const int r = wr * 64 + i * 16 + lrow;
        af[i] = *reinterpret_cast<const f16x8*>(
            &At[r][(h * 32 + lb * 8) ^ ((r & 7) << 3)]);
      }
#pragma unroll
      for (int j = 0; j < 4; j++) {
        const int r = wc * 64 + j * 16 + lrow;
        bf[j] = *reinterpret_cast<const f16x8*>(
            &Bs[r][(h * 32 + lb * 8) ^ ((r & 7) << 3)]);
      }
#pragma unroll
      for (int i = 0; i < 4; i++)
#pragma unroll
        for (int j = 0; j < 4; j++)
          acc[i][j] = __builtin_amdgcn_mfma_f32_16x16x32_f16(af[i], bf[j], acc[i][j], 0, 0, 0);
    }
    __syncthreads();
  }
#pragma unroll
  for (int i = 0; i < 4; i++) {
#pragma unroll
    for (int j = 0; j < 4; j++) {
      const int gcol = n0 + wc * 64 + j * 16 + lrow;
      if (gcol < Nv) {
        const float bv = bias[gcol];
#pragma unroll
        for (int r = 0; r < 4; r++) {
          const int grow = m0 + wr * 64 + i * 16 + lb * 4 + r;
          C[(size_t)grow * ldc + gcol] = acc[i][j][r] + bv;
        }
      }
    }
  }
}

// ---- ALL 5 QP iterations in one kernel (init_v fused). Block = 16 rows,
// 1024 threads (16 waves). Wave w = 16-col MFMA slice; Gh hoisted in registers
// (32 VGPRs), Gl read from L2 per iteration (round-25 exact, measured best);
// update thread = (j = tid&255, half = tid>>8) x 4 rows. 2 barriers/iter.
__global__ __launch_bounds__(1024) void qp_solve5(
    const _Float16* __restrict__ Gh, const _Float16* __restrict__ Gl,
    const float* __restrict__ beq, const float* __restrict__ zc,
    const float* __restrict__ NO, const float* __restrict__ ss,
    const float* __restrict__ p_smax, const float* __restrict__ p_smin,
    const float* __restrict__ p_sdmax, const float* __restrict__ p_sdmin,
    const float* __restrict__ p_sddmax, const float* __restrict__ p_sddmin,
    float* __restrict__ out, int B)
{
  __shared__ float xsA[16][264], xsB[16][264];
  __shared__ _Float16 vhs[16][264], vls[16][264];
  __shared__ float zcs[256], beqs[16];
  __shared__ float red[16][4][3];
  const int tid = threadIdx.x;
  const int wave = tid >> 6, lane = tid & 63;
  const int lr = lane & 15, lg = lane >> 4;
  const int m0 = blockIdx.x * 16;
  const int n0 = wave * 16;
  const int j = tid & 255, half = tid >> 8;    // half in 0..3

  const float smax = *p_smax, smin = *p_smin;
  const float sdmax = *p_sdmax, sdmin = *p_sdmin;
  const float sddmax = *p_sddmax, sddmin = *p_sddmin;
  const float K0 = smax + smin, K1 = sdmax + sdmin, K2 = sddmax + sddmin;
  const float invT = 20.f, invT2 = 400.f;
  const bool h1 = j < 255, h2 = j < 254;

  // ---- hoist Gh only (32 VGPRs) for this wave's 16-col slice ----
  f16x8 gh_r[8];
#pragma unroll
  for (int kk = 0; kk < 8; kk++) {
    const size_t bidx = (size_t)(n0 + lr) * 256 + kk * 32 + lg * 8;
    gh_r[kk] = *reinterpret_cast<const f16x8*>(&Gh[bidx]);
  }

  // ---- per-thread persistent state + FUSED init_v (round-8-validated formula) ----
  float lamr[4], ssv[4];
#pragma unroll
  for (int rr = 0; rr < 4; rr++) {
    const int rl = half * 4 + rr;
    const int gr = m0 + rl;
    const float* no = NO + (size_t)gr * NO_LD;
    ssv[rr] = ss[(size_t)gr * NUMV + j];
    lamr[rr] = no[j];
    const float D0 = K0 - fmaxf(0.f, no[256 + j]) + fmaxf(0.f, no[512 + j]);
    const float D1j = h1 ? (K1 - fmaxf(0.f, no[768 + j]) + fmaxf(0.f, no[1023 + j])) : 0.f;
    const float D1m = (j >= 1) ? (K1 - fmaxf(0.f, no[768 + j - 1]) + fmaxf(0.f, no[1023 + j - 1])) : 0.f;
    const float D2j = h2 ? (K2 - fmaxf(0.f, no[1278 + j]) + fmaxf(0.f, no[1532 + j])) : 0.f;
    const float D2m1 = (j >= 1 && h1) ? (K2 - fmaxf(0.f, no[1278 + j - 1]) + fmaxf(0.f, no[1532 + j - 1])) : 0.f;
    const float D2m2 = (j >= 2) ? (K2 - fmaxf(0.f, no[1278 + j - 2]) + fmaxf(0.f, no[1532 + j - 2])) : 0.f;
    const float vn = lamr[rr] + ssv[rr]
                   + D0 + (D1m - D1j) * invT + (D2m2 - 2.f * D2m1 + D2j) * invT2;
    const _Float16 vh16 = (_Float16)vn;
    vhs[rl][j] = vh16;
    vls[rl][j] = (_Float16)((vn - (float)vh16) * LSCALE);
  }
  if (tid < 256) zcs[tid] = zc[tid];
  if (tid < 16) {
    beqs[tid] = beq[m0 + tid];
    xsA[tid][0] = 0.f; xsA[tid][1] = 0.f; xsA[tid][258] = 0.f; xsA[tid][259] = 0.f;
    xsB[tid][0] = 0.f; xsB[tid][1] = 0.f; xsB[tid][258] = 0.f; xsB[tid][259] = 0.f;
  }
  float accP = 0.f, accF = 0.f;

  const size_t primOff = (size_t)B * NUMV;
  const size_t fpOff = primOff + (size_t)QP_ITERS * B;
  const size_t accPOff = fpOff + (size_t)QP_ITERS * B;
  const size_t accFOff = accPOff + (size_t)B;

  float (*xc)[264] = xsA;
  float (*xp)[264] = xsB;

  __syncthreads();    // staged vhs/vls/zcs/beqs ready

  for (int it = 0; it < QP_ITERS; ++it) {
    // ---- Phase 1: MFMA solve (validated split-fp16 path; Gh regs, Gl L2) ----
    f32x4 accH = (f32x4)0.0f, accL = (f32x4)0.0f;
#pragma unroll
    for (int kk = 0; kk < 8; kk++) {
      const f16x8 ah = *reinterpret_cast<const f16x8*>(&vhs[lr][kk * 32 + lg * 8]);
      const f16x8 al = *reinterpret_cast<const f16x8*>(&vls[lr][kk * 32 + lg * 8]);
      const f16x8 bl = *reinterpret_cast<const f16x8*>(
          &Gl[(size_t)(n0 + lr) * 256 + kk * 32 + lg * 8]);
      accH = __builtin_amdgcn_mfma_f32_16x16x32_f16(ah, gh_r[kk], accH, 0, 0, 0);
      accL = __builtin_amdgcn_mfma_f32_16x16x32_f16(ah, bl, accL, 0, 0, 0);
      accL = __builtin_amdgcn_mfma_f32_16x16x32_f16(al, gh_r[kk], accL, 0, 0, 0);
    }
    {
      const int r0l = lg * 4;
      const int col = n0 + lr;
      const float zv = zcs[col];
#pragma unroll
      for (int r = 0; r < 4; r++)
        xc[r0l + r][col + 2] = accH[r] + accL[r] * INV_LSCALE + beqs[r0l + r] * zv;
    }
    __syncthreads();    // x ready; previous red consumed

    // ---- Phase 2: update (validated local-recompute stencils), 4 rows/thread ----
#pragma unroll
    for (int rr = 0; rr < 4; rr++) {
      const int rl = half * 4 + rr;
      const int gr = m0 + rl;
      const float xm2 = xc[rl][j];
      const float xm1 = xc[rl][j + 1];
      const float x0  = xc[rl][j + 2];
      const float x1  = xc[rl][j + 3];
      const float x2  = xc[rl][j + 4];

      const float vj = (x1 - x0) * invT;
      const float aj = (x2 - 2.f * x1 + x0) * invT2;
      const float vm1 = (x0 - xm1) * invT;
      const float am1 = (x1 - 2.f * x0 + xm1) * invT2;
      const float am2 = (x0 - 2.f * xm1 + xm2) * invT2;

      const float rv0a = fmaxf(0.f, x0 - smax), rv0b = fmaxf(0.f, smin - x0);
      const float E0 = rv0a - rv0b;
      float rv1a = 0.f, rv1b = 0.f, rv2a = 0.f, rv2b = 0.f, E1 = 0.f, E2 = 0.f;
      if (h1) { rv1a = fmaxf(0.f, vj - sdmax); rv1b = fmaxf(0.f, sdmin - vj); E1 = rv1a - rv1b; }
      if (h2) { rv2a = fmaxf(0.f, aj - sddmax); rv2b = fmaxf(0.f, sddmin - aj); E2 = rv2a - rv2b; }
      float res2 = rv0a * rv0a + rv0b * rv0b + rv1a * rv1a + rv1b * rv1b
                 + rv2a * rv2a + rv2b * rv2b;

      const float E1m = (j >= 1) ? (fmaxf(0.f, vm1 - sdmax) - fmaxf(0.f, sdmin - vm1)) : 0.f;
      const float E2m1 = (j >= 1 && h1) ? (fmaxf(0.f, am1 - sddmax) - fmaxf(0.f, sddmin - am1)) : 0.f;
      const float E2m2 = (j >= 2) ? (fmaxf(0.f, am2 - sddmax) - fmaxf(0.f, sddmin - am2)) : 0.f;

      const float dl = E0 + (E1m - E1) * invT + (E2m2 - 2.f * E2m1 + E2) * invT2;
      const float lnew = lamr[rr] - dl;
      const float fpl2 = dl * dl;
      lamr[rr] = lnew;

      const float sn0a = fmaxf(0.f, smax - x0), sn0b = fmaxf(0.f, x0 - smin);
      float sn1a = 0.f, sn1b = 0.f, sn2a = 0.f, sn2b = 0.f;
      if (h1) { sn1a = fmaxf(0.f, sdmax - vj); sn1b = fmaxf(0.f, vj - sdmin); }
      if (h2) { sn2a = fmaxf(0.f, sddmax - aj); sn2b = fmaxf(0.f, aj - sddmin); }

      float sp0a, sp0b, sp1a = 0.f, sp1b = 0.f, sp2a = 0.f, sp2b = 0.f;
      if (it == 0) {
        const float* no = NO + (size_t)gr * NO_LD;
        sp0a = fmaxf(0.f, no[256 + j]); sp0b = fmaxf(0.f, no[512 + j]);
        if (h1) { sp1a = fmaxf(0.f, no[768 + j]); sp1b = fmaxf(0.f, no[1023 + j]); }
        if (h2) { sp2a = fmaxf(0.f, no[1278 + j]); sp2b = fmaxf(0.f, no[1532 + j]); }
      } else {
        const float p0 = xp[rl][j + 2], p1 = xp[rl][j + 3], p2 = xp[rl][j + 4];
        const float vp = (p1 - p0) * invT;
        const float ap = (p2 - 2.f * p1 + p0) * invT2;
        sp0a = fmaxf(0.f, smax - p0); sp0b = fmaxf(0.f, p0 - smin);
        if (h1) { sp1a = fmaxf(0.f, sdmax - vp); sp1b = fmaxf(0.f, vp - sdmin); }
        if (h2) { sp2a = fmaxf(0.f, sddmax - ap); sp2b = fmaxf(0.f, ap - sddmin); }
      }
      const float d0a = sp0a - sn0a, d0b = sp0b - sn0b;
      const float d1a = sp1a - sn1a, d1b = sp1b - sn1b;
      const float d2a = sp2a - sn2a, d2b = sp2b - sn2b;
      float fps2 = d0a * d0a + d0b * d0b + d1a * d1a + d1b * d1b
                 + d2a * d2a + d2b * d2b;

      const float D0 = fminf(smax, x0) + fmaxf(smin, x0);
      const float D1 = h1 ? (fminf(sdmax, vj) + fmaxf(sdmin, vj)) : 0.f;
      const float D2 = h2 ? (fminf(sddmax, aj) + fmaxf(sddmin, aj)) : 0.f;
      const float D1m = (j >= 1) ? (fminf(sdmax, vm1) + fmaxf(sdmin, vm1)) : 0.f;
      const float D2m1 = (j >= 1 && h1) ? (fminf(sddmax, am1) + fmaxf(sddmin, am1)) : 0.f;
      const float D2m2 = (j >= 2) ? (fminf(sddmax, am2) + fmaxf(sddmin, am2)) : 0.f;

      if (it < QP_ITERS - 1) {
        const float vn = lnew + ssv[rr]
                       + D0 + (D1m - D1) * invT + (D2m2 - 2.f * D2m1 + D2) * invT2;
        const _Float16 vh16 = (_Float16)vn;
        vhs[rl][j] = vh16;
        vls[rl][j] = (_Float16)((vn - (float)vh16) * LSCALE);
      } else {
        out[(size_t)gr * NUMV + j] = x0;
      }

      float a = res2, b = fps2, c = fpl2;
      for (int o = 32; o > 0; o >>= 1) {
        a += __shfl_down(a, o);
        b += __shfl_down(b, o);
        c += __shfl_down(c, o);
      }
      if (lane == 0) { red[wave][rr][0] = a; red[wave][rr][1] = b; red[wave][rr][2] = c; }
    }
    __syncthreads();    // red + vhs/vls ready; xp consumed

    if (tid < 16) {
      const int rl = tid, hf = rl >> 2, rr = rl & 3;
      const int w0 = hf * 4;
      const float r2 = red[w0][rr][0] + red[w0 + 1][rr][0] + red[w0 + 2][rr][0] + red[w0 + 3][rr][0];
      const float s2 = red[w0][rr][1] + red[w0 + 1][rr][1] + red[w0 + 2][rr][1] + red[w0 + 3][rr][1];
      const float l2 = red[w0][rr][2] + red[w0 + 1][rr][2] + red[w0 + 2][rr][2] + red[w0 + 3][rr][2];
      const float pr = sqrtf(r2);
      const float fp = sqrtf(s2) + sqrtf(l2);
      out[primOff + (size_t)it * B + m0 + rl] = pr;
      out[fpOff + (size_t)it * B + m0 + rl] = fp;
      accP += pr; accF += fp;
    }
    // swap x buffers
    float (*t)[264] = xc; xc = xp; xp = t;
  }
  if (tid < 16) {
    out[accPOff + m0 + tid] = accP * (1.f / QP_ITERS);
    out[accFOff + m0 + tid] = accF * (1.f / QP_ITERS);
  }
}

extern "C" void kernel_launch(void* const* d_in, const int* in_sizes, int n_in,
                              void* d_out, int out_size, void* d_ws, size_t ws_size,
                              hipStream_t stream)
{
  const float* inp = (const float*)d_in[0];       // [B][260]
  const float* sinit = (const float*)d_in[1];     // [B][1]
  const float* ssamp = (const float*)d_in[2];     // [B][256]
  const float* p_smax = (const float*)d_in[3];
  const float* p_smin = (const float*)d_in[4];
  const float* p_sdmax = (const float*)d_in[5];
  const float* p_sdmin = (const float*)d_in[6];
  const float* p_sddmax = (const float*)d_in[7];
  const float* p_sddmin = (const float*)d_in[8];
  const float* W1 = (const float*)d_in[11];       // [260][1024]
  const float* b1 = (const float*)d_in[12];       // [1024]
  const float* W2 = (const float*)d_in[13];       // [1024][1786]
  const float* b2 = (const float*)d_in[14];       // [1786]
  float* out = (float*)d_out;

  const int B = in_sizes[1];                      // 4096
  const int IND = in_sizes[9];                    // 260
  const int H = in_sizes[12];                     // 1024
  const int OUTN = in_sizes[14];                  // 1786

  char* ws = (char*)d_ws;
  float* NO = (float*)ws;                                      // [B][1792] fp32
  char* p = ws + (size_t)B * NO_LD * 4;                        // 29,360,128
  _Float16* hH = (_Float16*)p;                                 // [B][1024] fp16
  char* q = p + (size_t)B * H * 2;                             // 37,748,736
  _Float16* W2T = (_Float16*)q;                                // [1786][1024] fp16
  char* q2 = q + (size_t)OUTN * H * 2;                         // 41,406,464
  _Float16* W1T = (_Float16*)q2;                               // [1024][260] fp16
  char* r4 = ws + 46137344;                                    // 46,137,344
  _Float16* Gh = (_Float16*)r4;                                // [256][256] fp16
  _Float16* Gl = (_Float16*)(r4 + 131072);                     // [256][256] fp16 (x2048)
  float* zc = (float*)(r4 + 262144);                           // [256] fp32
  _Float16* Uh = (_Float16*)(r4 + 263168);                     // [256][256] fp16 (U^T)
  _Float16* Ul = (_Float16*)(r4 + 263168 + 131072);            // [256][256] fp16 (x2048)

  split_u<<<256, 256, 0, stream>>>(Uh, Ul, zc);
  {
    dim3 g(16, 8);
    gemm_g<<<g, 64, 0, stream>>>(Uh, Ul, Gh, Gl);
  }
  {
    dim3 g((IND + 31) / 32, (H + 31) / 32), blk(32, 8);
    transpose_cvt<<<g, blk, 0, stream>>>(W1, W1T, IND, H);
  }
  {
    dim3 g((H + 31) / 32, (OUTN + 31) / 32), blk(32, 8);
    transpose_cvt<<<g, blk, 0, stream>>>(W2, W2T, H, OUTN);
  }
  {
    dim3 g(B / 128, H / 128);
    mfma_gemm<true, true><<<g, 256, 0, stream>>>(inp, W1T, b1, hH, B, H, IND, IND, IND, H);
  }
  {
    dim3 g(B / 128, (OUTN + 127) / 128);
    mfma_gemm64<<<g, 256, 0, stream>>>(hH, W2T, b2, NO, B, OUTN, H, H, H, NO_LD);
  }
  qp_solve5<<<B / 16, 1024, 0, stream>>>(Gh, Gl, sinit, zc, NO, ssamp,
                                         p_smax, p_smin, p_sdmax, p_sdmin,
                                         p_sddmax, p_sddmin, out, B);
}

// Round 28
// 135.430 us; speedup vs baseline: 1.1341x; 1.0535x over previous
//
#include <hip/hip_runtime.h>
#include <cstddef>

// learned_qp_solver: B=4096, NUM=256, NC=1530, IND=260, H=1024, OUT=1786, 5 iters.
//
//   KKT solve closed form:  x = G v + (b_eq/z0) z,  G = C^{-1} - z z^T / z0 (symmetric)
//   MLP on matrix cores: v_mfma_f32_16x16x32_f16 (BK=32 GEMM1 / BK=64 GEMM2).
//   Solve: scaled split-fp16 (Gl,Vl x2048 dodge fp16 denormal flush in MFMA).
//   G build: U = L^{-1} at COMPILE TIME (constexpr quarters); gemm_g on MFMA.
//   qp_solve5: round-25 exact (frozen; rounds 17-26: all structural variants land
//   76-87us, 64-VGPR pin immovable).
//   Round-27 (validated, +9.6us): GEMM2 global_load_lds width=16 + both-sides
//   XOR swizzle.
//   Round-28: (a) split_u folded into gemm_g - reads __constant__ UFQ fp32
//   directly, identical split-fp16 conversion inline; one fewer dispatch, no
//   Uh/Ul round-trip. (b) GEMM1 B-staging -> global_load_lds (same technique
//   as GEMM2): W1T zero-padded to KP=288 (NaN guard: K-dim garbage would
//   contaminate all outputs; 16B reads never cross a 288-elem row), chunks of
//   16 rows, source pre-swizzle 8*((l&3)^((l>>2)&3)), read XOR (r&3)<<3.
//
// ws layout (bytes), ~46.7 MB:
//   [0,          29360128)  NO   fp32 [B][1792]
//   [29360128,   37748736)  hH   fp16 [B][1024]
//   [37748736,   41406464)  W2T  fp16 [1786][1024]
//   [41406464,   41996288)  W1T  fp16 [1024][288]  (zero-padded K)
//   [46137344,   46268416)  Gh   fp16 [256][256]
//   [46268416,   46399488)  Gl   fp16 [256][256]  (scaled x2048)
//   [46399488,   46400512)  zc   fp32 [256]

#define NUMV 256
#define QP_ITERS 5
#define NO_LD 1792
#define LSCALE 2048.0f
#define INV_LSCALE (1.0f / 2048.0f)

typedef _Float16 f16x4 __attribute__((ext_vector_type(4)));
typedef _Float16 f16x8 __attribute__((ext_vector_type(8)));
typedef float f32x4 __attribute__((ext_vector_type(4)));

// ---------------- compile-time pentadiagonal Cholesky tables ----------------
struct FacT {
  double invd[256];
  double l1[257];
  double l2[258];
  double z[256];
  float  zcf[256];
};

constexpr double csqrt_(double x) {
  double g = (x > 1.0) ? x : 1.0;
  for (int i = 0; i < 64; ++i) g = 0.5 * (g + x / g);
  return g;
}

constexpr FacT make_fac() {
  FacT f{};
  const double T = 0.05, a = 1.0 / (T * T), b2 = a * a;
  double c0[256] = {}, c1[255] = {}, c2[254] = {};
  double dd[256] = {}, l1[256] = {}, l2[256] = {};
  for (int j = 0; j < 256; j++) {
    double cd1 = (j == 0 || j == 255) ? 1.0 : 2.0;
    double cd2 = (j == 0 || j == 255) ? 1.0 : ((j == 1 || j == 254) ? 5.0 : 6.0);
    c0[j] = 3.0 + 2.0 * a * cd1 + 2.0 * b2 * cd2;
  }
  for (int j = 0; j < 255; j++) c1[j] = -2.0 * a + 2.0 * b2 * ((j == 0 || j == 254) ? -2.0 : -4.0);
  for (int j = 0; j < 254; j++) c2[j] = 2.0 * b2;
  dd[0] = csqrt_(c0[0]); l1[0] = 0.0; l2[0] = 0.0;
  l1[1] = c1[0] / dd[0]; l2[1] = 0.0;
  dd[1] = csqrt_(c0[1] - l1[1] * l1[1]);
  for (int j = 2; j < 256; j++) {
    l2[j] = c2[j - 2] / dd[j - 2];
    l1[j] = (c1[j - 1] - l2[j] * l1[j - 1]) / dd[j - 1];
    dd[j] = csqrt_(c0[j] - l1[j] * l1[j] - l2[j] * l2[j]);
  }
  for (int j = 0; j < 256; j++) f.invd[j] = 1.0 / dd[j];
  for (int j = 0; j < 256; j++) f.l1[j] = l1[j];
  f.l1[256] = 0.0;
  for (int j = 0; j < 256; j++) f.l2[j] = l2[j];
  f.l2[256] = 0.0; f.l2[257] = 0.0;
  double w[256] = {}, zz[256] = {};
  w[0] = 1.0 / dd[0];
  w[1] = (-l1[1] * w[0]) / dd[1];
  for (int j = 2; j < 256; j++) w[j] = (-l1[j] * w[j - 1] - l2[j] * w[j - 2]) / dd[j];
  zz[255] = w[255] / dd[255];
  zz[254] = (w[254] - l1[255] * zz[255]) / dd[254];
  for (int j = 253; j >= 0; j--)
    zz[j] = (w[j] - l1[j + 1] * zz[j + 1] - l2[j + 2] * zz[j + 2]) / dd[j];
  for (int j = 0; j < 256; j++) f.z[j] = zz[j];
  for (int j = 0; j < 256; j++) f.zcf[j] = (float)(zz[j] / zz[0]);
  return f;
}

constexpr FacT FAC_HOST = make_fac();
__constant__ FacT FAC = FAC_HOST;

// ---- compile-time U = L^{-1}: quarter (64 columns) per constexpr evaluation ----
struct UQ { float u[64][256]; };

constexpr UQ make_uq(int cbase) {
  UQ q{};
  const double T = 0.05, a = 1.0 / (T * T), b2 = a * a;
  double c0a[256] = {}, c1a[255] = {}, c2a[254] = {};
  double dd[256] = {}, l1[256] = {}, l2[256] = {};
  for (int j = 0; j < 256; j++) {
    double cd1 = (j == 0 || j == 255) ? 1.0 : 2.0;
    double cd2 = (j == 0 || j == 255) ? 1.0 : ((j == 1 || j == 254) ? 5.0 : 6.0);
    c0a[j] = 3.0 + 2.0 * a * cd1 + 2.0 * b2 * cd2;
  }
  for (int j = 0; j < 255; j++) c1a[j] = -2.0 * a + 2.0 * b2 * ((j == 0 || j == 254) ? -2.0 : -4.0);
  for (int j = 0; j < 254; j++) c2a[j] = 2.0 * b2;
  dd[0] = csqrt_(c0a[0]); l1[0] = 0.0; l2[0] = 0.0;
  l1[1] = c1a[0] / dd[0]; l2[1] = 0.0;
  dd[1] = csqrt_(c0a[1] - l1[1] * l1[1]);
  for (int j = 2; j < 256; j++) {
    l2[j] = c2a[j - 2] / dd[j - 2];
    l1[j] = (c1a[j - 1] - l2[j] * l1[j - 1]) / dd[j - 1];
    dd[j] = csqrt_(c0a[j] - l1[j] * l1[j] - l2[j] * l2[j]);
  }
  for (int c = cbase; c < cbase + 64; ++c) {
    double w1 = 0.0, w2 = 0.0;
    for (int j = c; j < 256; ++j) {
      const double rhs = (j == c) ? 1.0 : 0.0;
      const double wj = (rhs - l1[j] * w1 - l2[j] * w2) / dd[j];
      q.u[c - cbase][j] = (float)wj;
      w2 = w1; w1 = wj;
    }
  }
  return q;
}

constexpr UQ UQ0_H = make_uq(0);
constexpr UQ UQ1_H = make_uq(64);
constexpr UQ UQ2_H = make_uq(128);
constexpr UQ UQ3_H = make_uq(192);
__constant__ UQ UFQ0 = UQ0_H;
__constant__ UQ UFQ1 = UQ1_H;
__constant__ UQ UFQ2 = UQ2_H;
__constant__ UQ UFQ3 = UQ3_H;

__device__ __forceinline__ const float* uq_row(int c) {
  if (c < 64)  return UFQ0.u[c];
  if (c < 128) return UFQ1.u[c - 64];
  if (c < 192) return UFQ2.u[c - 128];
  return UFQ3.u[c - 192];
}

// identical arithmetic to the old split_u conversion
__device__ __forceinline__ void split8(const float* __restrict__ w, f16x8& h, f16x8& l) {
#pragma unroll
  for (int e = 0; e < 8; e++) {
    const float x = w[e];
    const _Float16 hh = (_Float16)x;
    h[e] = hh;
    l[e] = (_Float16)((x - (float)hh) * LSCALE);
  }
}

// ---- G = UT * UT^T - z z^T/z0 via split-fp16 MFMA, reading compile-time UFQ
// directly (split_u folded in; conversion arithmetic identical). Writes zc. ----
__global__ __launch_bounds__(64) void gemm_g(
    _Float16* __restrict__ Gh, _Float16* __restrict__ Gl, float* __restrict__ zc)
{
  const int lane = threadIdx.x;
  const int lr = lane & 15, lg = lane >> 4;
  const int m0 = blockIdx.x * 16, n0 = blockIdx.y * 32;
  if (blockIdx.x == 0 && blockIdx.y == 0) {
    for (int t = lane; t < 256; t += 64) zc[t] = FAC.zcf[t];
  }
  f32x4 accH[2], accL[2];
#pragma unroll
  for (int nf = 0; nf < 2; nf++) { accH[nf] = (f32x4)0.0f; accL[nf] = (f32x4)0.0f; }
  const float* arow = uq_row(m0 + lr);
  const float* brow0 = uq_row(n0 + lr);
  const float* brow1 = uq_row(n0 + 16 + lr);
#pragma unroll 2
  for (int k0 = 0; k0 < 256; k0 += 32) {
    f16x8 ah, al;
    split8(arow + k0 + lg * 8, ah, al);
#pragma unroll
    for (int nf = 0; nf < 2; nf++) {
      f16x8 bh, bl;
      split8((nf ? brow1 : brow0) + k0 + lg * 8, bh, bl);
      accH[nf] = __builtin_amdgcn_mfma_f32_16x16x32_f16(ah, bh, accH[nf], 0, 0, 0);
      accL[nf] = __builtin_amdgcn_mfma_f32_16x16x32_f16(ah, bl, accL[nf], 0, 0, 0);
      accL[nf] = __builtin_amdgcn_mfma_f32_16x16x32_f16(al, bh, accL[nf], 0, 0, 0);
    }
  }
  const int row0 = m0 + lg * 4;
#pragma unroll
  for (int nf = 0; nf < 2; nf++) {
    const int col = n0 + nf * 16 + lr;
    const double zcd = FAC.z[col] / FAC.z[0];
#pragma unroll
    for (int r = 0; r < 4; r++) {
      const int row = row0 + r;
      const float g = accH[nf][r] + accL[nf][r] * INV_LSCALE
                    - (float)(FAC.z[row] * zcd);
      const _Float16 gh = (_Float16)g;
      Gh[(size_t)row * 256 + col] = gh;
      Gl[(size_t)row * 256 + col] = (_Float16)((g - (float)gh) * LSCALE);
    }
  }
}

// -------- transpose + fp32->fp16 convert: in [K][N] -> out [N][KP], zero-pad K..KP --------
__global__ __launch_bounds__(256) void transpose_cvt(
    const float* __restrict__ in, _Float16* __restrict__ out, int K, int N, int KP)
{
  __shared__ float t[32][33];
  const int bk = blockIdx.x * 32, bn = blockIdx.y * 32;
  const int x = threadIdx.x, y = threadIdx.y;
  for (int yy = y; yy < 32; yy += 8) {
    const int k = bk + yy, n = bn + x;
    t[yy][x] = (k < K && n < N) ? in[(size_t)k * N + n] : 0.f;
  }
  __syncthreads();
  for (int yy = y; yy < 32; yy += 8) {
    const int n = bn + yy, k = bk + x;
    if (n < N && k < KP) out[(size_t)n * KP + k] = (_Float16)t[x][yy];
  }
}

// ---------------- MFMA GEMM (BK=32, fp32 A + K tails; B via global_load_lds): GEMM1 ----
// B (W1T) is [N][288] zero-padded -> 16B loads at k0+kswz (max 280..288) never
// cross a row and never read garbage. Swizzle: chunk = 16 rows x 32 f16 = 1KB;
// lane l -> row (l>>2), source k pre-swizzled 8*((l&3)^((l>>2)&3)); fragment
// reads XOR (r&3)<<3. A-side unchanged (reg-staged fp32->fp16, zeroed tail).
template<bool A_FP32, bool OUT_H16>
__global__ __launch_bounds__(256) void mfma_gemm(
    const void* __restrict__ Av, const _Float16* __restrict__ Bt,
    const float* __restrict__ bias, void* __restrict__ Cv,
    int M, int Nv, int K, int lda, int ldk, int ldc)
{
  __shared__ _Float16 At[128][40];
  __shared__ _Float16 Bs[128][32];
  const int tid = threadIdx.x;
  const int lane = tid & 63, wid = tid >> 6;
  const int wr = wid >> 1, wc = wid & 1;
  const int lrow = lane & 15, lb = lane >> 4;
  const int m0 = blockIdx.x * 128, n0 = blockIdx.y * 128;
  const int srow = tid >> 1, skh = (tid & 1) * 16;

  // B gload_lds geometry
  const int rl4 = lane >> 2;                        // row within 16-row chunk
  const int kswz = 8 * ((lane & 3) ^ (rl4 & 3));    // pre-swizzled k offset

  f32x4 acc[4][4];
#pragma unroll
  for (int i = 0; i < 4; i++)
#pragma unroll
    for (int j = 0; j < 4; j++) acc[i][j] = (f32x4)0.0f;

  const int nsteps = (K + 31) / 32;
  for (int t = 0; t < nsteps; ++t) {
    const int k0 = t * 32;
    if (A_FP32) {
      const float* A = (const float*)Av;
#pragma unroll
      for (int i = 0; i < 4; i++) {
        const int k = k0 + skh + i * 4;
        f16x4 hv = {};
        if (k + 4 <= K) {
          const float4 v = *reinterpret_cast<const float4*>(&A[(size_t)(m0 + srow) * lda + k]);
          hv[0] = (_Float16)v.x; hv[1] = (_Float16)v.y;
          hv[2] = (_Float16)v.z; hv[3] = (_Float16)v.w;
        } else if (k < K) {
          for (int e = 0; e < 4; e++)
            if (k + e < K) hv[e] = (_Float16)A[(size_t)(m0 + srow) * lda + k + e];
        }
        *reinterpret_cast<f16x4*>(&At[srow][skh + i * 4]) = hv;
      }
    } else {
      const _Float16* A = (const _Float16*)Av;
#pragma unroll
      for (int i = 0; i < 4; i++) {
        const int k = k0 + skh + i * 4;
        f16x4 hv = {};
        if (k + 4 <= K) hv = *reinterpret_cast<const f16x4*>(&A[(size_t)(m0 + srow) * lda + k]);
        *reinterpret_cast<f16x4*>(&At[srow][skh + i * 4]) = hv;
      }
    }
    {
#pragma unroll
      for (int c = 0; c < 2; ++c) {
        const int ci = wid * 2 + c;                 // chunk 0..7 (wave-uniform)
        const _Float16* bsrc = &Bt[(size_t)(n0 + ci * 16 + rl4) * ldk + k0 + kswz];
        __builtin_amdgcn_global_load_lds(
            (const __attribute__((address_space(1))) void*)bsrc,
            (__attribute__((address_space(3))) void*)(&Bs[ci * 16][0]), 16, 0, 0);
      }
    }
    __syncthreads();
    f16x8 af[4], bf[4];
#pragma unroll
    for (int i = 0; i < 4; i++)
      af[i] = *reinterpret_cast<const f16x8*>(&At[wr * 64 + i * 16 + lrow][lb * 8]);
#pragma unroll
    for (int j = 0; j < 4; j++) {
      const int r = wc * 64 + j * 16 + lrow;
      bf[j] = *reinterpret_cast<const f16x8*>(&Bs[r][(lb * 8) ^ ((r & 3) << 3)]);
    }
#pragma unroll
    for (int i = 0; i < 4; i++)
#pragma unroll
      for (int j = 0; j < 4; j++)
        acc[i][j] = __builtin_amdgcn_mfma_f32_16x16x32_f16(af[i], bf[j], acc[i][j], 0, 0, 0);
    __syncthreads();
  }
#pragma unroll
  for (int i = 0; i < 4; i++) {
#pragma unroll
    for (int j = 0; j < 4; j++) {
      const int gcol = n0 + wc * 64 + j * 16 + lrow;
      if (gcol < Nv) {
        const float bv = bias[gcol];
#pragma unroll
        for (int r = 0; r < 4; r++) {
          const int grow = m0 + wr * 64 + i * 16 + lb * 4 + r;
          float v = acc[i][j][r] + bv;
          if (OUT_H16) {
            v = fmaxf(v, 0.f);
            ((_Float16*)Cv)[(size_t)grow * ldc + gcol] = (_Float16)v;
          } else {
            ((float*)Cv)[(size_t)grow * ldc + gcol] = v;
          }
        }
      }
    }
  }
}

// ---------------- MFMA GEMM BK=64 (fp16 A, K%64==0, M%128==0, fp32 out): GEMM2 ----
// Round-27 (validated +9.6us): global_load_lds width=16 staging + both-sides XOR
// swizzle. B n-tail garbage only contaminates discarded output cols (gcol<Nv).
__global__ __launch_bounds__(256) void mfma_gemm64(
    const _Float16* __restrict__ A, const _Float16* __restrict__ Bt,
    const float* __restrict__ bias, float* __restrict__ C,
    int M, int Nv, int K, int lda, int ldk, int ldc)
{
  __shared__ _Float16 At[128][64];
  __shared__ _Float16 Bs[128][64];
  const int tid = threadIdx.x;
  const int lane = tid & 63, wid = tid >> 6;
  const int wr = wid >> 1, wc = wid & 1;
  const int lrow = lane & 15, lb = lane >> 4;
  const int m0 = blockIdx.x * 128, n0 = blockIdx.y * 128;

  const int srow8 = lane >> 3;                 // row within chunk (0..7)
  const int kswz = 8 * ((lane & 7) ^ srow8);   // pre-swizzled k offset (f16 units)

  f32x4 acc[4][4];
#pragma unroll
  for (int i = 0; i < 4; i++)
#pragma unroll
    for (int j = 0; j < 4; j++) acc[i][j] = (f32x4)0.0f;

  const int nsteps = K >> 6;
  for (int t = 0; t < nsteps; ++t) {
    const int k0 = t * 64;
#pragma unroll
    for (int c = 0; c < 4; ++c) {
      const int ci = wid * 4 + c;              // chunk 0..15 (wave-uniform)
      const int row = ci * 8 + srow8;
      const _Float16* asrc = &A[(size_t)(m0 + row) * lda + k0 + kswz];
      const _Float16* bsrc = &Bt[(size_t)(n0 + row) * ldk + k0 + kswz];
      __builtin_amdgcn_global_load_lds(
          (const __attribute__((address_space(1))) void*)asrc,
          (__attribute__((address_space(3))) void*)(&At[ci * 8][0]), 16, 0, 0);
      __builtin_amdgcn_global_load_lds(
          (const __attribute__((address_space(1))) void*)bsrc,
          (__attribute__((address_space(3))) void*)(&Bs[ci * 8][0]), 16, 0, 0);
    }
    __syncthreads();
#pragma unroll
    for (int h = 0; h < 2; h++) {
      f16x8 af[4], bf[4];
#pragma unroll
      for (int i = 0; i < 4; i++) {
        const int r = wr * 64 + i * 16 + lrow;
        af[i] = *reinterpret_cast<const f16x8*>(
            &At[r][(h * 32 + lb * 8) ^ ((r & 7) << 3)]);
      }
#pragma unroll
      for (int j = 0; j < 4; j++) {
        const int r = wc * 64 + j * 16 + lrow;
        bf[j] = *reinterpret_cast<const f16x8*>(
            &Bs[r][(h * 32 + lb * 8) ^ ((r & 7) << 3)]);
      }
#pragma unroll
      for (int i = 0; i < 4; i++)
#pragma unroll
        for (int j = 0; j < 4; j++)
          acc[i][j] = __builtin_amdgcn_mfma_f32_16x16x32_f16(af[i], bf[j], acc[i][j], 0, 0, 0);
    }
    __syncthreads();
  }
#pragma unroll
  for (int i = 0; i < 4; i++) {
#pragma unroll
    for (int j = 0; j < 4; j++) {
      const int gcol = n0 + wc * 64 + j * 16 + lrow;
      if (gcol < Nv) {
        const float bv = bias[gcol];
#pragma unroll
        for (int r = 0; r < 4; r++) {
          const int grow = m0 + wr * 64 + i * 16 + lb * 4 + r;
          C[(size_t)grow * ldc + gcol] = acc[i][j][r] + bv;
        }
      }
    }
  }
}

// ---- ALL 5 QP iterations in one kernel (init_v fused). Block = 16 rows,
// 1024 threads (16 waves). Wave w = 16-col MFMA slice; Gh hoisted in registers
// (32 VGPRs), Gl read from L2 per iteration (round-25 exact, measured best);
// update thread = (j = tid&255, half = tid>>8) x 4 rows. 2 barriers/iter.
__global__ __launch_bounds__(1024) void qp_solve5(
    const _Float16* __restrict__ Gh, const _Float16* __restrict__ Gl,
    const float* __restrict__ beq, const float* __restrict__ zc,
    const float* __restrict__ NO, const float* __restrict__ ss,
    const float* __restrict__ p_smax, const float* __restrict__ p_smin,
    const float* __restrict__ p_sdmax, const float* __restrict__ p_sdmin,
    const float* __restrict__ p_sddmax, const float* __restrict__ p_sddmin,
    float* __restrict__ out, int B)
{
  __shared__ float xsA[16][264], xsB[16][264];
  __shared__ _Float16 vhs[16][264], vls[16][264];
  __shared__ float zcs[256], beqs[16];
  __shared__ float red[16][4][3];
  const int tid = threadIdx.x;
  const int wave = tid >> 6, lane = tid & 63;
  const int lr = lane & 15, lg = lane >> 4;
  const int m0 = blockIdx.x * 16;
  const int n0 = wave * 16;
  const int j = tid & 255, half = tid >> 8;    // half in 0..3

  const float smax = *p_smax, smin = *p_smin;
  const float sdmax = *p_sdmax, sdmin = *p_sdmin;
  const float sddmax = *p_sddmax, sddmin = *p_sddmin;
  const float K0 = smax + smin, K1 = sdmax + sdmin, K2 = sddmax + sddmin;
  const float invT = 20.f, invT2 = 400.f;
  const bool h1 = j < 255, h2 = j < 254;

  // ---- hoist Gh only (32 VGPRs) for this wave's 16-col slice ----
  f16x8 gh_r[8];
#pragma unroll
  for (int kk = 0; kk < 8; kk++) {
    const size_t bidx = (size_t)(n0 + lr) * 256 + kk * 32 + lg * 8;
    gh_r[kk] = *reinterpret_cast<const f16x8*>(&Gh[bidx]);
  }

  // ---- per-thread persistent state + FUSED init_v (round-8-validated formula) ----
  float lamr[4], ssv[4];
#pragma unroll
  for (int rr = 0; rr < 4; rr++) {
    const int rl = half * 4 + rr;
    const int gr = m0 + rl;
    const float* no = NO + (size_t)gr * NO_LD;
    ssv[rr] = ss[(size_t)gr * NUMV + j];
    lamr[rr] = no[j];
    const float D0 = K0 - fmaxf(0.f, no[256 + j]) + fmaxf(0.f, no[512 + j]);
    const float D1j = h1 ? (K1 - fmaxf(0.f, no[768 + j]) + fmaxf(0.f, no[1023 + j])) : 0.f;
    const float D1m = (j >= 1) ? (K1 - fmaxf(0.f, no[768 + j - 1]) + fmaxf(0.f, no[1023 + j - 1])) : 0.f;
    const float D2j = h2 ? (K2 - fmaxf(0.f, no[1278 + j]) + fmaxf(0.f, no[1532 + j])) : 0.f;
    const float D2m1 = (j >= 1 && h1) ? (K2 - fmaxf(0.f, no[1278 + j - 1]) + fmaxf(0.f, no[1532 + j - 1])) : 0.f;
    const float D2m2 = (j >= 2) ? (K2 - fmaxf(0.f, no[1278 + j - 2]) + fmaxf(0.f, no[1532 + j - 2])) : 0.f;
    const float vn = lamr[rr] + ssv[rr]
                   + D0 + (D1m - D1j) * invT + (D2m2 - 2.f * D2m1 + D2j) * invT2;
    const _Float16 vh16 = (_Float16)vn;
    vhs[rl][j] = vh16;
    vls[rl][j] = (_Float16)((vn - (float)vh16) * LSCALE);
  }
  if (tid < 256) zcs[tid] = zc[tid];
  if (tid < 16) {
    beqs[tid] = beq[m0 + tid];
    xsA[tid][0] = 0.f; xsA[tid][1] = 0.f; xsA[tid][258] = 0.f; xsA[tid][259] = 0.f;
    xsB[tid][0] = 0.f; xsB[tid][1] = 0.f; xsB[tid][258] = 0.f; xsB[tid][259] = 0.f;
  }
  float accP = 0.f, accF = 0.f;

  const size_t primOff = (size_t)B * NUMV;
  const size_t fpOff = primOff + (size_t)QP_ITERS * B;
  const size_t accPOff = fpOff + (size_t)QP_ITERS * B;
  const size_t accFOff = accPOff + (size_t)B;

  float (*xc)[264] = xsA;
  float (*xp)[264] = xsB;

  __syncthreads();    // staged vhs/vls/zcs/beqs ready

  for (int it = 0; it < QP_ITERS; ++it) {
    // ---- Phase 1: MFMA solve (validated split-fp16 path; Gh regs, Gl L2) ----
    f32x4 accH = (f32x4)0.0f, accL = (f32x4)0.0f;
#pragma unroll
    for (int kk = 0; kk < 8; kk++) {
      const f16x8 ah = *reinterpret_cast<const f16x8*>(&vhs[lr][kk * 32 + lg * 8]);
      const f16x8 al = *reinterpret_cast<const f16x8*>(&vls[lr][kk * 32 + lg * 8]);
      const f16x8 bl = *reinterpret_cast<const f16x8*>(
          &Gl[(size_t)(n0 + lr) * 256 + kk * 32 + lg * 8]);
      accH = __builtin_amdgcn_mfma_f32_16x16x32_f16(ah, gh_r[kk], accH, 0, 0, 0);
      accL = __builtin_amdgcn_mfma_f32_16x16x32_f16(ah, bl, accL, 0, 0, 0);
      accL = __builtin_amdgcn_mfma_f32_16x16x32_f16(al, gh_r[kk], accL, 0, 0, 0);
    }
    {
      const int r0l = lg * 4;
      const int col = n0 + lr;
      const float zv = zcs[col];
#pragma unroll
      for (int r = 0; r < 4; r++)
        xc[r0l + r][col + 2] = accH[r] + accL[r] * INV_LSCALE + beqs[r0l + r] * zv;
    }
    __syncthreads();    // x ready; previous red consumed

    // ---- Phase 2: update (validated local-recompute stencils), 4 rows/thread ----
#pragma unroll
    for (int rr = 0; rr < 4; rr++) {
      const int rl = half * 4 + rr;
      const int gr = m0 + rl;
      const float xm2 = xc[rl][j];
      const float xm1 = xc[rl][j + 1];
      const float x0  = xc[rl][j + 2];
      const float x1  = xc[rl][j + 3];
      const float x2  = xc[rl][j + 4];

      const float vj = (x1 - x0) * invT;
      const float aj = (x2 - 2.f * x1 + x0) * invT2;
      const float vm1 = (x0 - xm1) * invT;
      const float am1 = (x1 - 2.f * x0 + xm1) * invT2;
      const float am2 = (x0 - 2.f * xm1 + xm2) * invT2;

      const float rv0a = fmaxf(0.f, x0 - smax), rv0b = fmaxf(0.f, smin - x0);
      const float E0 = rv0a - rv0b;
      float rv1a = 0.f, rv1b = 0.f, rv2a = 0.f, rv2b = 0.f, E1 = 0.f, E2 = 0.f;
      if (h1) { rv1a = fmaxf(0.f, vj - sdmax); rv1b = fmaxf(0.f, sdmin - vj); E1 = rv1a - rv1b; }
      if (h2) { rv2a = fmaxf(0.f, aj - sddmax); rv2b = fmaxf(0.f, sddmin - aj); E2 = rv2a - rv2b; }
      float res2 = rv0a * rv0a + rv0b * rv0b + rv1a * rv1a + rv1b * rv1b
                 + rv2a * rv2a + rv2b * rv2b;

      const float E1m = (j >= 1) ? (fmaxf(0.f, vm1 - sdmax) - fmaxf(0.f, sdmin - vm1)) : 0.f;
      const float E2m1 = (j >= 1 && h1) ? (fmaxf(0.f, am1 - sddmax) - fmaxf(0.f, sddmin - am1)) : 0.f;
      const float E2m2 = (j >= 2) ? (fmaxf(0.f, am2 - sddmax) - fmaxf(0.f, sddmin - am2)) : 0.f;

      const float dl = E0 + (E1m - E1) * invT + (E2m2 - 2.f * E2m1 + E2) * invT2;
      const float lnew = lamr[rr] - dl;
      const float fpl2 = dl * dl;
      lamr[rr] = lnew;

      const float sn0a = fmaxf(0.f, smax - x0), sn0b = fmaxf(0.f, x0 - smin);
      float sn1a = 0.f, sn1b = 0.f, sn2a = 0.f, sn2b = 0.f;
      if (h1) { sn1a = fmaxf(0.f, sdmax - vj); sn1b = fmaxf(0.f, vj - sdmin); }
      if (h2) { sn2a = fmaxf(0.f, sddmax - aj); sn2b = fmaxf(0.f, aj - sddmin); }

      float sp0a, sp0b, sp1a = 0.f, sp1b = 0.f, sp2a = 0.f, sp2b = 0.f;
      if (it == 0) {
        const float* no = NO + (size_t)gr * NO_LD;
        sp0a = fmaxf(0.f, no[256 + j]); sp0b = fmaxf(0.f, no[512 + j]);
        if (h1) { sp1a = fmaxf(0.f, no[768 + j]); sp1b = fmaxf(0.f, no[1023 + j]); }
        if (h2) { sp2a = fmaxf(0.f, no[1278 + j]); sp2b = fmaxf(0.f, no[1532 + j]); }
      } else {
        const float p0 = xp[rl][j + 2], p1 = xp[rl][j + 3], p2 = xp[rl][j + 4];
        const float vp = (p1 - p0) * invT;
        const float ap = (p2 - 2.f * p1 + p0) * invT2;
        sp0a = fmaxf(0.f, smax - p0); sp0b = fmaxf(0.f, p0 - smin);
        if (h1) { sp1a = fmaxf(0.f, sdmax - vp); sp1b = fmaxf(0.f, vp - sdmin); }
        if (h2) { sp2a = fmaxf(0.f, sddmax - ap); sp2b = fmaxf(0.f, ap - sddmin); }
      }
      const float d0a = sp0a - sn0a, d0b = sp0b - sn0b;
      const float d1a = sp1a - sn1a, d1b = sp1b - sn1b;
      const float d2a = sp2a - sn2a, d2b = sp2b - sn2b;
      float fps2 = d0a * d0a + d0b * d0b + d1a * d1a + d1b * d1b
                 + d2a * d2a + d2b * d2b;

      const float D0 = fminf(smax, x0) + fmaxf(smin, x0);
      const float D1 = h1 ? (fminf(sdmax, vj) + fmaxf(sdmin, vj)) : 0.f;
      const float D2 = h2 ? (fminf(sddmax, aj) + fmaxf(sddmin, aj)) : 0.f;
      const float D1m = (j >= 1) ? (fminf(sdmax, vm1) + fmaxf(sdmin, vm1)) : 0.f;
      const float D2m1 = (j >= 1 && h1) ? (fminf(sddmax, am1) + fmaxf(sddmin, am1)) : 0.f;
      const float D2m2 = (j >= 2) ? (fminf(sddmax, am2) + fmaxf(sddmin, am2)) : 0.f;

      if (it < QP_ITERS - 1) {
        const float vn = lnew + ssv[rr]
                       + D0 + (D1m - D1) * invT + (D2m2 - 2.f * D2m1 + D2) * invT2;
        const _Float16 vh16 = (_Float16)vn;
        vhs[rl][j] = vh16;
        vls[rl][j] = (_Float16)((vn - (float)vh16) * LSCALE);
      } else {
        out[(size_t)gr * NUMV + j] = x0;
      }

      float a = res2, b = fps2, c = fpl2;
      for (int o = 32; o > 0; o >>= 1) {
        a += __shfl_down(a, o);
        b += __shfl_down(b, o);
        c += __shfl_down(c, o);
      }
      if (lane == 0) { red[wave][rr][0] = a; red[wave][rr][1] = b; red[wave][rr][2] = c; }
    }
    __syncthreads();    // red + vhs/vls ready; xp consumed

    if (tid < 16) {
      const int rl = tid, hf = rl >> 2, rr = rl & 3;
      const int w0 = hf * 4;
      const float r2 = red[w0][rr][0] + red[w0 + 1][rr][0] + red[w0 + 2][rr][0] + red[w0 + 3][rr][0];
      const float s2 = red[w0][rr][1] + red[w0 + 1][rr][1] + red[w0 + 2][rr][1] + red[w0 + 3][rr][1];
      const float l2 = red[w0][rr][2] + red[w0 + 1][rr][2] + red[w0 + 2][rr][2] + red[w0 + 3][rr][2];
      const float pr = sqrtf(r2);
      const float fp = sqrtf(s2) + sqrtf(l2);
      out[primOff + (size_t)it * B + m0 + rl] = pr;
      out[fpOff + (size_t)it * B + m0 + rl] = fp;
      accP += pr; accF += fp;
    }
    // swap x buffers
    float (*t)[264] = xc; xc = xp; xp = t;
  }
  if (tid < 16) {
    out[accPOff + m0 + tid] = accP * (1.f / QP_ITERS);
    out[accFOff + m0 + tid] = accF * (1.f / QP_ITERS);
  }
}

extern "C" void kernel_launch(void* const* d_in, const int* in_sizes, int n_in,
                              void* d_out, int out_size, void* d_ws, size_t ws_size,
                              hipStream_t stream)
{
  const float* inp = (const float*)d_in[0];       // [B][260]
  const float* sinit = (const float*)d_in[1];     // [B][1]
  const float* ssamp = (const float*)d_in[2];     // [B][256]
  const float* p_smax = (const float*)d_in[3];
  const float* p_smin = (const float*)d_in[4];
  const float* p_sdmax = (const float*)d_in[5];
  const float* p_sdmin = (const float*)d_in[6];
  const float* p_sddmax = (const float*)d_in[7];
  const float* p_sddmin = (const float*)d_in[8];
  const float* W1 = (const float*)d_in[11];       // [260][1024]
  const float* b1 = (const float*)d_in[12];       // [1024]
  const float* W2 = (const float*)d_in[13];       // [1024][1786]
  const float* b2 = (const float*)d_in[14];       // [1786]
  float* out = (float*)d_out;

  const int B = in_sizes[1];                      // 4096
  const int IND = in_sizes[9];                    // 260
  const int H = in_sizes[12];                     // 1024
  const int OUTN = in_sizes[14];                  // 1786
  const int KP1 = 288;                            // GEMM1 padded K (9 x 32)

  char* ws = (char*)d_ws;
  float* NO = (float*)ws;                                      // [B][1792] fp32
  char* p = ws + (size_t)B * NO_LD * 4;                        // 29,360,128
  _Float16* hH = (_Float16*)p;                                 // [B][1024] fp16
  char* q = p + (size_t)B * H * 2;                             // 37,748,736
  _Float16* W2T = (_Float16*)q;                                // [1786][1024] fp16
  char* q2 = q + (size_t)OUTN * H * 2;                         // 41,406,464
  _Float16* W1T = (_Float16*)q2;                               // [1024][288] fp16 (padded)
  char* r4 = ws + 46137344;                                    // 46,137,344
  _Float16* Gh = (_Float16*)r4;                                // [256][256] fp16
  _Float16* Gl = (_Float16*)(r4 + 131072);                     // [256][256] fp16 (x2048)
  float* zc = (float*)(r4 + 262144);                           // [256] fp32

  {
    dim3 g(16, 8);
    gemm_g<<<g, 64, 0, stream>>>(Gh, Gl, zc);
  }
  {
    dim3 g((KP1 + 31) / 32, (H + 31) / 32), blk(32, 8);
    transpose_cvt<<<g, blk, 0, stream>>>(W1, W1T, IND, H, KP1);
  }
  {
    dim3 g((H + 31) / 32, (OUTN + 31) / 32), blk(32, 8);
    transpose_cvt<<<g, blk, 0, stream>>>(W2, W2T, H, OUTN, H);
  }
  {
    dim3 g(B / 128, H / 128);
    mfma_gemm<true, true><<<g, 256, 0, stream>>>(inp, W1T, b1, hH, B, H, IND, IND, KP1, H);
  }
  {
    dim3 g(B / 128, (OUTN + 127) / 128);
    mfma_gemm64<<<g, 256, 0, stream>>>(hH, W2T, b2, NO, B, OUTN, H, H, H, NO_LD);
  }
  qp_solve5<<<B / 16, 1024, 0, stream>>>(Gh, Gl, sinit, zc, NO, ssamp,
                                         p_smax, p_smin, p_sdmax, p_sdmin,
                                         p_sddmax, p_sddmin, out, B);
}

// Round 29
// 119.226 us; speedup vs baseline: 1.2883x; 1.1359x over previous
//
#include <hip/hip_runtime.h>
#include <cstddef>

// learned_qp_solver: B=4096, NUM=256, NC=1530, IND=260, H=1024, OUT=1786, 5 iters.
//
//   KKT solve closed form:  x = G v + (b_eq/z0) z,  G = C^{-1} - z z^T / z0 (symmetric)
//   MLP on matrix cores: v_mfma_f32_16x16x32_f16 (BK=32 GEMM1 / BK=64 GEMM2).
//   Solve: scaled split-fp16 (Gl,Vl x2048 dodge fp16 denormal flush in MFMA).
//   G build: U = L^{-1} at COMPILE TIME (constexpr quarters); gemm_g on MFMA.
//   qp_solve5: round-25 exact (frozen; rounds 17-26: all variants 76-87us).
//   Round-27 (validated +9.6us): GEMM2 global_load_lds + both-sides XOR swizzle.
//   Round-28 (validated +7.2us): split_u folded into gemm_g; GEMM1 B-side
//   global_load_lds with zero-padded W1T [1024][288].
//   Round-29: (a) ALL preprocessing merged into ONE dispatch `prep` (gemm_g +
//   W1/W2 transposes + NEW inp->fp16 [B][288] zero-pad convert; independent
//   sub-tasks branched on blockIdx; barriers only in transpose branch) ->
//   4 dispatches+3 gaps become 1. (b) GEMM1 -> BOTH-sides global_load_lds
//   (round-28-validated chunk geometry), A pre-converted fp16 padded so no
//   K-garbage and identical arithmetic (same casts, zeros in pad).
//
// ws layout (bytes), ~46.7 MB:
//   [0,          29360128)  NO   fp32 [B][1792]
//   [29360128,   37748736)  hH   fp16 [B][1024]
//   [37748736,   41406464)  W2T  fp16 [1786][1024]
//   [41406464,   41996288)  W1T  fp16 [1024][288]  (zero-padded K)
//   [41996288,   44355584)  hA   fp16 [4096][288]  (zero-padded K)
//   [46137344,   46268416)  Gh   fp16 [256][256]
//   [46268416,   46399488)  Gl   fp16 [256][256]  (scaled x2048)
//   [46399488,   46400512)  zc   fp32 [256]

#define NUMV 256
#define QP_ITERS 5
#define NO_LD 1792
#define LSCALE 2048.0f
#define INV_LSCALE (1.0f / 2048.0f)

typedef _Float16 f16x4 __attribute__((ext_vector_type(4)));
typedef _Float16 f16x8 __attribute__((ext_vector_type(8)));
typedef float f32x4 __attribute__((ext_vector_type(4)));

// ---------------- compile-time pentadiagonal Cholesky tables ----------------
struct FacT {
  double invd[256];
  double l1[257];
  double l2[258];
  double z[256];
  float  zcf[256];
};

constexpr double csqrt_(double x) {
  double g = (x > 1.0) ? x : 1.0;
  for (int i = 0; i < 64; ++i) g = 0.5 * (g + x / g);
  return g;
}

constexpr FacT make_fac() {
  FacT f{};
  const double T = 0.05, a = 1.0 / (T * T), b2 = a * a;
  double c0[256] = {}, c1[255] = {}, c2[254] = {};
  double dd[256] = {}, l1[256] = {}, l2[256] = {};
  for (int j = 0; j < 256; j++) {
    double cd1 = (j == 0 || j == 255) ? 1.0 : 2.0;
    double cd2 = (j == 0 || j == 255) ? 1.0 : ((j == 1 || j == 254) ? 5.0 : 6.0);
    c0[j] = 3.0 + 2.0 * a * cd1 + 2.0 * b2 * cd2;
  }
  for (int j = 0; j < 255; j++) c1[j] = -2.0 * a + 2.0 * b2 * ((j == 0 || j == 254) ? -2.0 : -4.0);
  for (int j = 0; j < 254; j++) c2[j] = 2.0 * b2;
  dd[0] = csqrt_(c0[0]); l1[0] = 0.0; l2[0] = 0.0;
  l1[1] = c1[0] / dd[0]; l2[1] = 0.0;
  dd[1] = csqrt_(c0[1] - l1[1] * l1[1]);
  for (int j = 2; j < 256; j++) {
    l2[j] = c2[j - 2] / dd[j - 2];
    l1[j] = (c1[j - 1] - l2[j] * l1[j - 1]) / dd[j - 1];
    dd[j] = csqrt_(c0[j] - l1[j] * l1[j] - l2[j] * l2[j]);
  }
  for (int j = 0; j < 256; j++) f.invd[j] = 1.0 / dd[j];
  for (int j = 0; j < 256; j++) f.l1[j] = l1[j];
  f.l1[256] = 0.0;
  for (int j = 0; j < 256; j++) f.l2[j] = l2[j];
  f.l2[256] = 0.0; f.l2[257] = 0.0;
  double w[256] = {}, zz[256] = {};
  w[0] = 1.0 / dd[0];
  w[1] = (-l1[1] * w[0]) / dd[1];
  for (int j = 2; j < 256; j++) w[j] = (-l1[j] * w[j - 1] - l2[j] * w[j - 2]) / dd[j];
  zz[255] = w[255] / dd[255];
  zz[254] = (w[254] - l1[255] * zz[255]) / dd[254];
  for (int j = 253; j >= 0; j--)
    zz[j] = (w[j] - l1[j + 1] * zz[j + 1] - l2[j + 2] * zz[j + 2]) / dd[j];
  for (int j = 0; j < 256; j++) f.z[j] = zz[j];
  for (int j = 0; j < 256; j++) f.zcf[j] = (float)(zz[j] / zz[0]);
  return f;
}

constexpr FacT FAC_HOST = make_fac();
__constant__ FacT FAC = FAC_HOST;

// ---- compile-time U = L^{-1}: quarter (64 columns) per constexpr evaluation ----
struct UQ { float u[64][256]; };

constexpr UQ make_uq(int cbase) {
  UQ q{};
  const double T = 0.05, a = 1.0 / (T * T), b2 = a * a;
  double c0a[256] = {}, c1a[255] = {}, c2a[254] = {};
  double dd[256] = {}, l1[256] = {}, l2[256] = {};
  for (int j = 0; j < 256; j++) {
    double cd1 = (j == 0 || j == 255) ? 1.0 : 2.0;
    double cd2 = (j == 0 || j == 255) ? 1.0 : ((j == 1 || j == 254) ? 5.0 : 6.0);
    c0a[j] = 3.0 + 2.0 * a * cd1 + 2.0 * b2 * cd2;
  }
  for (int j = 0; j < 255; j++) c1a[j] = -2.0 * a + 2.0 * b2 * ((j == 0 || j == 254) ? -2.0 : -4.0);
  for (int j = 0; j < 254; j++) c2a[j] = 2.0 * b2;
  dd[0] = csqrt_(c0a[0]); l1[0] = 0.0; l2[0] = 0.0;
  l1[1] = c1a[0] / dd[0]; l2[1] = 0.0;
  dd[1] = csqrt_(c0a[1] - l1[1] * l1[1]);
  for (int j = 2; j < 256; j++) {
    l2[j] = c2a[j - 2] / dd[j - 2];
    l1[j] = (c1a[j - 1] - l2[j] * l1[j - 1]) / dd[j - 1];
    dd[j] = csqrt_(c0a[j] - l1[j] * l1[j] - l2[j] * l2[j]);
  }
  for (int c = cbase; c < cbase + 64; ++c) {
    double w1 = 0.0, w2 = 0.0;
    for (int j = c; j < 256; ++j) {
      const double rhs = (j == c) ? 1.0 : 0.0;
      const double wj = (rhs - l1[j] * w1 - l2[j] * w2) / dd[j];
      q.u[c - cbase][j] = (float)wj;
      w2 = w1; w1 = wj;
    }
  }
  return q;
}

constexpr UQ UQ0_H = make_uq(0);
constexpr UQ UQ1_H = make_uq(64);
constexpr UQ UQ2_H = make_uq(128);
constexpr UQ UQ3_H = make_uq(192);
__constant__ UQ UFQ0 = UQ0_H;
__constant__ UQ UFQ1 = UQ1_H;
__constant__ UQ UFQ2 = UQ2_H;
__constant__ UQ UFQ3 = UQ3_H;

__device__ __forceinline__ const float* uq_row(int c) {
  if (c < 64)  return UFQ0.u[c];
  if (c < 128) return UFQ1.u[c - 64];
  if (c < 192) return UFQ2.u[c - 128];
  return UFQ3.u[c - 192];
}

// identical arithmetic to the original split_u conversion
__device__ __forceinline__ void split8(const float* __restrict__ w, f16x8& h, f16x8& l) {
#pragma unroll
  for (int e = 0; e < 8; e++) {
    const float x = w[e];
    const _Float16 hh = (_Float16)x;
    h[e] = hh;
    l[e] = (_Float16)((x - (float)hh) * LSCALE);
  }
}

// ---- gemm_g body (round-28 exact, parameterized block coords; 64 threads) ----
__device__ void gemm_g_body(
    _Float16* __restrict__ Gh, _Float16* __restrict__ Gl, float* __restrict__ zc,
    int gx, int gy, int lane)
{
  const int lr = lane & 15, lg = lane >> 4;
  const int m0 = gx * 16, n0 = gy * 32;
  if (gx == 0 && gy == 0) {
    for (int t = lane; t < 256; t += 64) zc[t] = FAC.zcf[t];
  }
  f32x4 accH[2], accL[2];
#pragma unroll
  for (int nf = 0; nf < 2; nf++) { accH[nf] = (f32x4)0.0f; accL[nf] = (f32x4)0.0f; }
  const float* arow = uq_row(m0 + lr);
  const float* brow0 = uq_row(n0 + lr);
  const float* brow1 = uq_row(n0 + 16 + lr);
#pragma unroll 2
  for (int k0 = 0; k0 < 256; k0 += 32) {
    f16x8 ah, al;
    split8(arow + k0 + lg * 8, ah, al);
#pragma unroll
    for (int nf = 0; nf < 2; nf++) {
      f16x8 bh, bl;
      split8((nf ? brow1 : brow0) + k0 + lg * 8, bh, bl);
      accH[nf] = __builtin_amdgcn_mfma_f32_16x16x32_f16(ah, bh, accH[nf], 0, 0, 0);
      accL[nf] = __builtin_amdgcn_mfma_f32_16x16x32_f16(ah, bl, accL[nf], 0, 0, 0);
      accL[nf] = __builtin_amdgcn_mfma_f32_16x16x32_f16(al, bh, accL[nf], 0, 0, 0);
    }
  }
  const int row0 = m0 + lg * 4;
#pragma unroll
  for (int nf = 0; nf < 2; nf++) {
    const int col = n0 + nf * 16 + lr;
    const double zcd = FAC.z[col] / FAC.z[0];
#pragma unroll
    for (int r = 0; r < 4; r++) {
      const int row = row0 + r;
      const float g = accH[nf][r] + accL[nf][r] * INV_LSCALE
                    - (float)(FAC.z[row] * zcd);
      const _Float16 gh = (_Float16)g;
      Gh[(size_t)row * 256 + col] = gh;
      Gl[(size_t)row * 256 + col] = (_Float16)((g - (float)gh) * LSCALE);
    }
  }
}

// ---- transpose body (round-28 exact, 1-D 256 threads, parameterized coords) ----
__device__ void transpose_body(
    const float* __restrict__ in, _Float16* __restrict__ out,
    int K, int N, int KP, int bx, int by, int tid)
{
  __shared__ float t[32][33];
  const int bk = bx * 32, bn = by * 32;
  const int x = tid & 31, y = tid >> 5;
  for (int yy = y; yy < 32; yy += 8) {
    const int k = bk + yy, n = bn + x;
    t[yy][x] = (k < K && n < N) ? in[(size_t)k * N + n] : 0.f;
  }
  __syncthreads();
  for (int yy = y; yy < 32; yy += 8) {
    const int n = bn + yy, k = bk + x;
    if (n < N && k < KP) out[(size_t)n * KP + k] = (_Float16)t[x][yy];
  }
}

// ---- ONE preprocessing dispatch: gemm_g | W1->W1T | W2->W2T | inp->hA pad ----
// Sub-tasks are fully independent; branch on flattened blockIdx. Barriers only
// inside the transpose branch (all 256 threads of those blocks participate).
#define PREP_G   128   // gemm_g: (16,8)
#define PREP_T1  288   // W1T: (288/32=9, 1024/32=32)
#define PREP_T2  1792  // W2T: (1024/32=32, 1792/32=56)
#define PREP_CV  256   // hA: 4096/16 rows per block
__global__ __launch_bounds__(256) void prep(
    _Float16* __restrict__ Gh, _Float16* __restrict__ Gl, float* __restrict__ zc,
    const float* __restrict__ W1, _Float16* __restrict__ W1T,
    const float* __restrict__ W2, _Float16* __restrict__ W2T,
    const float* __restrict__ inp, _Float16* __restrict__ hA,
    int IND, int OUTN)
{
  const int bid = blockIdx.x;
  const int tid = threadIdx.x;
  if (bid < PREP_G) {
    if (tid < 64) gemm_g_body(Gh, Gl, zc, bid & 15, bid >> 4, tid);
  } else if (bid < PREP_G + PREP_T1) {
    const int i = bid - PREP_G;
    transpose_body(W1, W1T, IND, 1024, 288, i % 9, i / 9, tid);
  } else if (bid < PREP_G + PREP_T1 + PREP_T2) {
    const int i = bid - PREP_G - PREP_T1;
    transpose_body(W2, W2T, 1024, OUTN, 1024, i & 31, i >> 5, tid);
  } else {
    const int r0 = (bid - PREP_G - PREP_T1 - PREP_T2) * 16;
    for (int idx = tid; idx < 16 * 288; idx += 256) {
      const int r = r0 + idx / 288, c = idx % 288;
      hA[(size_t)r * 288 + c] =
          (c < IND) ? (_Float16)inp[(size_t)r * IND + c] : (_Float16)0.f;
    }
  }
}

// ---------------- MFMA GEMM BK=32, BOTH sides global_load_lds: GEMM1 ----------------
// A = hA fp16 [4096][288] zero-padded, B = W1T fp16 [1024][288] zero-padded ->
// 16B loads at k0+kswz (max 280+8=288) never cross a row, never read garbage.
// Round-28-validated chunk geometry: chunk = 16 rows x 32 f16 = 1KB; lane l ->
// row l>>2, source k pre-swizzled 8*((l&3)^((l>>2)&3)); reads XOR (r&3)<<3.
__global__ __launch_bounds__(256) void mfma_gemm32(
    const _Float16* __restrict__ A, const _Float16* __restrict__ Bt,
    const float* __restrict__ bias, _Float16* __restrict__ C,
    int KP, int ldc)
{
  __shared__ _Float16 At[128][32];
  __shared__ _Float16 Bs[128][32];
  const int tid = threadIdx.x;
  const int lane = tid & 63, wid = tid >> 6;
  const int wr = wid >> 1, wc = wid & 1;
  const int lrow = lane & 15, lb = lane >> 4;
  const int m0 = blockIdx.x * 128, n0 = blockIdx.y * 128;
  const int rl4 = lane >> 2;
  const int kswz = 8 * ((lane & 3) ^ (rl4 & 3));

  f32x4 acc[4][4];
#pragma unroll
  for (int i = 0; i < 4; i++)
#pragma unroll
    for (int j = 0; j < 4; j++) acc[i][j] = (f32x4)0.0f;

  const int nsteps = KP >> 5;
  for (int t = 0; t < nsteps; ++t) {
    const int k0 = t * 32;
#pragma unroll
    for (int c = 0; c < 2; ++c) {
      const int ci = wid * 2 + c;                 // chunk 0..7 (wave-uniform)
      const _Float16* asrc = &A[(size_t)(m0 + ci * 16 + rl4) * KP + k0 + kswz];
      const _Float16* bsrc = &Bt[(size_t)(n0 + ci * 16 + rl4) * KP + k0 + kswz];
      __builtin_amdgcn_global_load_lds(
          (const __attribute__((address_space(1))) void*)asrc,
          (__attribute__((address_space(3))) void*)(&At[ci * 16][0]), 16, 0, 0);
      __builtin_amdgcn_global_load_lds(
          (const __attribute__((address_space(1))) void*)bsrc,
          (__attribute__((address_space(3))) void*)(&Bs[ci * 16][0]), 16, 0, 0);
    }
    __syncthreads();
    f16x8 af[4], bf[4];
#pragma unroll
    for (int i = 0; i < 4; i++) {
      const int r = wr * 64 + i * 16 + lrow;
      af[i] = *reinterpret_cast<const f16x8*>(&At[r][(lb * 8) ^ ((r & 3) << 3)]);
    }
#pragma unroll
    for (int j = 0; j < 4; j++) {
      const int r = wc * 64 + j * 16 + lrow;
      bf[j] = *reinterpret_cast<const f16x8*>(&Bs[r][(lb * 8) ^ ((r & 3) << 3)]);
    }
#pragma unroll
    for (int i = 0; i < 4; i++)
#pragma unroll
      for (int j = 0; j < 4; j++)
        acc[i][j] = __builtin_amdgcn_mfma_f32_16x16x32_f16(af[i], bf[j], acc[i][j], 0, 0, 0);
    __syncthreads();
  }
#pragma unroll
  for (int i = 0; i < 4; i++) {
#pragma unroll
    for (int j = 0; j < 4; j++) {
      const int gcol = n0 + wc * 64 + j * 16 + lrow;
      const float bv = bias[gcol];
#pragma unroll
      for (int r = 0; r < 4; r++) {
        const int grow = m0 + wr * 64 + i * 16 + lb * 4 + r;
        const float v = fmaxf(acc[i][j][r] + bv, 0.f);
        C[(size_t)grow * ldc + gcol] = (_Float16)v;
      }
    }
  }
}

// ---------------- MFMA GEMM BK=64 (fp16 A, K%64==0, M%128==0, fp32 out): GEMM2 ----
// Round-27 (validated +9.6us): global_load_lds width=16 staging + both-sides XOR
// swizzle. B n-tail garbage only contaminates discarded output cols (gcol<Nv).
__global__ __launch_bounds__(256) void mfma_gemm64(
    const _Float16* __restrict__ A, const _Float16* __restrict__ Bt,
    const float* __restrict__ bias, float* __restrict__ C,
    int M, int Nv, int K, int lda, int ldk, int ldc)
{
  __shared__ _Float16 At[128][64];
  __shared__ _Float16 Bs[128][64];
  const int tid = threadIdx.x;
  const int lane = tid & 63, wid = tid >> 6;
  const int wr = wid >> 1, wc = wid & 1;
  const int lrow = lane & 15, lb = lane >> 4;
  const int m0 = blockIdx.x * 128, n0 = blockIdx.y * 128;

  const int srow8 = lane >> 3;                 // row within chunk (0..7)
  const int kswz = 8 * ((lane & 7) ^ srow8);   // pre-swizzled k offset (f16 units)

  f32x4 acc[4][4];
#pragma unroll
  for (int i = 0; i < 4; i++)
#pragma unroll
    for (int j = 0; j < 4; j++) acc[i][j] = (f32x4)0.0f;

  const int nsteps = K >> 6;
  for (int t = 0; t < nsteps; ++t) {
    const int k0 = t * 64;
#pragma unroll
    for (int c = 0; c < 4; ++c) {
      const int ci = wid * 4 + c;              // chunk 0..15 (wave-uniform)
      const int row = ci * 8 + srow8;
      const _Float16* asrc = &A[(size_t)(m0 + row) * lda + k0 + kswz];
      const _Float16* bsrc = &Bt[(size_t)(n0 + row) * ldk + k0 + kswz];
      __builtin_amdgcn_global_load_lds(
          (const __attribute__((address_space(1))) void*)asrc,
          (__attribute__((address_space(3))) void*)(&At[ci * 8][0]), 16, 0, 0);
      __builtin_amdgcn_global_load_lds(
          (const __attribute__((address_space(1))) void*)bsrc,
          (__attribute__((address_space(3))) void*)(&Bs[ci * 8][0]), 16, 0, 0);
    }
    __syncthreads();
#pragma unroll
    for (int h = 0; h < 2; h++) {
      f16x8 af[4], bf[4];
#pragma unroll
      for (int i = 0; i < 4; i++) {
        const int r = wr * 64 + i * 16 + lrow;
        af[i] = *reinterpret_cast<const f16x8*>(
            &At[r][(h * 32 + lb * 8) ^ ((r & 7) << 3)]);
      }
#pragma unroll
      for (int j = 0; j < 4; j++) {
        const int r = wc * 64 + j * 16 + lrow;
        bf[j] = *reinterpret_cast<const f16x8*>(
            &Bs[r][(h * 32 + lb * 8) ^ ((r & 7) << 3)]);
      }
#pragma unroll
      for (int i = 0; i < 4; i++)
#pragma unroll
        for (int j = 0; j < 4; j++)
          acc[i][j] = __builtin_amdgcn_mfma_f32_16x16x32_f16(af[i], bf[j], acc[i][j], 0, 0, 0);
    }
    __syncthreads();
  }
#pragma unroll
  for (int i = 0; i < 4; i++) {
#pragma unroll
    for (int j = 0; j < 4; j++) {
      const int gcol = n0 + wc * 64 + j * 16 + lrow;
      if (gcol < Nv) {
        const float bv = bias[gcol];
#pragma unroll
        for (int r = 0; r < 4; r++) {
          const int grow = m0 + wr * 64 + i * 16 + lb * 4 + r;
          C[(size_t)grow * ldc + gcol] = acc[i][j][r] + bv;
        }
      }
    }
  }
}

// ---- ALL 5 QP iterations in one kernel (init_v fused). Block = 16 rows,
// 1024 threads (16 waves). Wave w = 16-col MFMA slice; Gh hoisted in registers
// (32 VGPRs), Gl read from L2 per iteration (round-25 exact, measured best);
// update thread = (j = tid&255, half = tid>>8) x 4 rows. 2 barriers/iter.
__global__ __launch_bounds__(1024) void qp_solve5(
    const _Float16* __restrict__ Gh, const _Float16* __restrict__ Gl,
    const float* __restrict__ beq, const float* __restrict__ zc,
    const float* __restrict__ NO, const float* __restrict__ ss,
    const float* __restrict__ p_smax, const float* __restrict__ p_smin,
    const float* __restrict__ p_sdmax, const float* __restrict__ p_sdmin,
    const float* __restrict__ p_sddmax, const float* __restrict__ p_sddmin,
    float* __restrict__ out, int B)
{
  __shared__ float xsA[16][264], xsB[16][264];
  __shared__ _Float16 vhs[16][264], vls[16][264];
  __shared__ float zcs[256], beqs[16];
  __shared__ float red[16][4][3];
  const int tid = threadIdx.x;
  const int wave = tid >> 6, lane = tid & 63;
  const int lr = lane & 15, lg = lane >> 4;
  const int m0 = blockIdx.x * 16;
  const int n0 = wave * 16;
  const int j = tid & 255, half = tid >> 8;    // half in 0..3

  const float smax = *p_smax, smin = *p_smin;
  const float sdmax = *p_sdmax, sdmin = *p_sdmin;
  const float sddmax = *p_sddmax, sddmin = *p_sddmin;
  const float K0 = smax + smin, K1 = sdmax + sdmin, K2 = sddmax + sddmin;
  const float invT = 20.f, invT2 = 400.f;
  const bool h1 = j < 255, h2 = j < 254;

  // ---- hoist Gh only (32 VGPRs) for this wave's 16-col slice ----
  f16x8 gh_r[8];
#pragma unroll
  for (int kk = 0; kk < 8; kk++) {
    const size_t bidx = (size_t)(n0 + lr) * 256 + kk * 32 + lg * 8;
    gh_r[kk] = *reinterpret_cast<const f16x8*>(&Gh[bidx]);
  }

  // ---- per-thread persistent state + FUSED init_v (round-8-validated formula) ----
  float lamr[4], ssv[4];
#pragma unroll
  for (int rr = 0; rr < 4; rr++) {
    const int rl = half * 4 + rr;
    const int gr = m0 + rl;
    const float* no = NO + (size_t)gr * NO_LD;
    ssv[rr] = ss[(size_t)gr * NUMV + j];
    lamr[rr] = no[j];
    const float D0 = K0 - fmaxf(0.f, no[256 + j]) + fmaxf(0.f, no[512 + j]);
    const float D1j = h1 ? (K1 - fmaxf(0.f, no[768 + j]) + fmaxf(0.f, no[1023 + j])) : 0.f;
    const float D1m = (j >= 1) ? (K1 - fmaxf(0.f, no[768 + j - 1]) + fmaxf(0.f, no[1023 + j - 1])) : 0.f;
    const float D2j = h2 ? (K2 - fmaxf(0.f, no[1278 + j]) + fmaxf(0.f, no[1532 + j])) : 0.f;
    const float D2m1 = (j >= 1 && h1) ? (K2 - fmaxf(0.f, no[1278 + j - 1]) + fmaxf(0.f, no[1532 + j - 1])) : 0.f;
    const float D2m2 = (j >= 2) ? (K2 - fmaxf(0.f, no[1278 + j - 2]) + fmaxf(0.f, no[1532 + j - 2])) : 0.f;
    const float vn = lamr[rr] + ssv[rr]
                   + D0 + (D1m - D1j) * invT + (D2m2 - 2.f * D2m1 + D2j) * invT2;
    const _Float16 vh16 = (_Float16)vn;
    vhs[rl][j] = vh16;
    vls[rl][j] = (_Float16)((vn - (float)vh16) * LSCALE);
  }
  if (tid < 256) zcs[tid] = zc[tid];
  if (tid < 16) {
    beqs[tid] = beq[m0 + tid];
    xsA[tid][0] = 0.f; xsA[tid][1] = 0.f; xsA[tid][258] = 0.f; xsA[tid][259] = 0.f;
    xsB[tid][0] = 0.f; xsB[tid][1] = 0.f; xsB[tid][258] = 0.f; xsB[tid][259] = 0.f;
  }
  float accP = 0.f, accF = 0.f;

  const size_t primOff = (size_t)B * NUMV;
  const size_t fpOff = primOff + (size_t)QP_ITERS * B;
  const size_t accPOff = fpOff + (size_t)QP_ITERS * B;
  const size_t accFOff = accPOff + (size_t)B;

  float (*xc)[264] = xsA;
  float (*xp)[264] = xsB;

  __syncthreads();    // staged vhs/vls/zcs/beqs ready

  for (int it = 0; it < QP_ITERS; ++it) {
    // ---- Phase 1: MFMA solve (validated split-fp16 path; Gh regs, Gl L2) ----
    f32x4 accH = (f32x4)0.0f, accL = (f32x4)0.0f;
#pragma unroll
    for (int kk = 0; kk < 8; kk++) {
      const f16x8 ah = *reinterpret_cast<const f16x8*>(&vhs[lr][kk * 32 + lg * 8]);
      const f16x8 al = *reinterpret_cast<const f16x8*>(&vls[lr][kk * 32 + lg * 8]);
      const f16x8 bl = *reinterpret_cast<const f16x8*>(
          &Gl[(size_t)(n0 + lr) * 256 + kk * 32 + lg * 8]);
      accH = __builtin_amdgcn_mfma_f32_16x16x32_f16(ah, gh_r[kk], accH, 0, 0, 0);
      accL = __builtin_amdgcn_mfma_f32_16x16x32_f16(ah, bl, accL, 0, 0, 0);
      accL = __builtin_amdgcn_mfma_f32_16x16x32_f16(al, gh_r[kk], accL, 0, 0, 0);
    }
    {
      const int r0l = lg * 4;
      const int col = n0 + lr;
      const float zv = zcs[col];
#pragma unroll
      for (int r = 0; r < 4; r++)
        xc[r0l + r][col + 2] = accH[r] + accL[r] * INV_LSCALE + beqs[r0l + r] * zv;
    }
    __syncthreads();    // x ready; previous red consumed

    // ---- Phase 2: update (validated local-recompute stencils), 4 rows/thread ----
#pragma unroll
    for (int rr = 0; rr < 4; rr++) {
      const int rl = half * 4 + rr;
      const int gr = m0 + rl;
      const float xm2 = xc[rl][j];
      const float xm1 = xc[rl][j + 1];
      const float x0  = xc[rl][j + 2];
      const float x1  = xc[rl][j + 3];
      const float x2  = xc[rl][j + 4];

      const float vj = (x1 - x0) * invT;
      const float aj = (x2 - 2.f * x1 + x0) * invT2;
      const float vm1 = (x0 - xm1) * invT;
      const float am1 = (x1 - 2.f * x0 + xm1) * invT2;
      const float am2 = (x0 - 2.f * xm1 + xm2) * invT2;

      const float rv0a = fmaxf(0.f, x0 - smax), rv0b = fmaxf(0.f, smin - x0);
      const float E0 = rv0a - rv0b;
      float rv1a = 0.f, rv1b = 0.f, rv2a = 0.f, rv2b = 0.f, E1 = 0.f, E2 = 0.f;
      if (h1) { rv1a = fmaxf(0.f, vj - sdmax); rv1b = fmaxf(0.f, sdmin - vj); E1 = rv1a - rv1b; }
      if (h2) { rv2a = fmaxf(0.f, aj - sddmax); rv2b = fmaxf(0.f, sddmin - aj); E2 = rv2a - rv2b; }
      float res2 = rv0a * rv0a + rv0b * rv0b + rv1a * rv1a + rv1b * rv1b
                 + rv2a * rv2a + rv2b * rv2b;

      const float E1m = (j >= 1) ? (fmaxf(0.f, vm1 - sdmax) - fmaxf(0.f, sdmin - vm1)) : 0.f;
      const float E2m1 = (j >= 1 && h1) ? (fmaxf(0.f, am1 - sddmax) - fmaxf(0.f, sddmin - am1)) : 0.f;
      const float E2m2 = (j >= 2) ? (fmaxf(0.f, am2 - sddmax) - fmaxf(0.f, sddmin - am2)) : 0.f;

      const float dl = E0 + (E1m - E1) * invT + (E2m2 - 2.f * E2m1 + E2) * invT2;
      const float lnew = lamr[rr] - dl;
      const float fpl2 = dl * dl;
      lamr[rr] = lnew;

      const float sn0a = fmaxf(0.f, smax - x0), sn0b = fmaxf(0.f, x0 - smin);
      float sn1a = 0.f, sn1b = 0.f, sn2a = 0.f, sn2b = 0.f;
      if (h1) { sn1a = fmaxf(0.f, sdmax - vj); sn1b = fmaxf(0.f, vj - sdmin); }
      if (h2) { sn2a = fmaxf(0.f, sddmax - aj); sn2b = fmaxf(0.f, aj - sddmin); }

      float sp0a, sp0b, sp1a = 0.f, sp1b = 0.f, sp2a = 0.f, sp2b = 0.f;
      if (it == 0) {
        const float* no = NO + (size_t)gr * NO_LD;
        sp0a = fmaxf(0.f, no[256 + j]); sp0b = fmaxf(0.f, no[512 + j]);
        if (h1) { sp1a = fmaxf(0.f, no[768 + j]); sp1b = fmaxf(0.f, no[1023 + j]); }
        if (h2) { sp2a = fmaxf(0.f, no[1278 + j]); sp2b = fmaxf(0.f, no[1532 + j]); }
      } else {
        const float p0 = xp[rl][j + 2], p1 = xp[rl][j + 3], p2 = xp[rl][j + 4];
        const float vp = (p1 - p0) * invT;
        const float ap = (p2 - 2.f * p1 + p0) * invT2;
        sp0a = fmaxf(0.f, smax - p0); sp0b = fmaxf(0.f, p0 - smin);
        if (h1) { sp1a = fmaxf(0.f, sdmax - vp); sp1b = fmaxf(0.f, vp - sdmin); }
        if (h2) { sp2a = fmaxf(0.f, sddmax - ap); sp2b = fmaxf(0.f, ap - sddmin); }
      }
      const float d0a = sp0a - sn0a, d0b = sp0b - sn0b;
      const float d1a = sp1a - sn1a, d1b = sp1b - sn1b;
      const float d2a = sp2a - sn2a, d2b = sp2b - sn2b;
      float fps2 = d0a * d0a + d0b * d0b + d1a * d1a + d1b * d1b
                 + d2a * d2a + d2b * d2b;

      const float D0 = fminf(smax, x0) + fmaxf(smin, x0);
      const float D1 = h1 ? (fminf(sdmax, vj) + fmaxf(sdmin, vj)) : 0.f;
      const float D2 = h2 ? (fminf(sddmax, aj) + fmaxf(sddmin, aj)) : 0.f;
      const float D1m = (j >= 1) ? (fminf(sdmax, vm1) + fmaxf(sdmin, vm1)) : 0.f;
      const float D2m1 = (j >= 1 && h1) ? (fminf(sddmax, am1) + fmaxf(sddmin, am1)) : 0.f;
      const float D2m2 = (j >= 2) ? (fminf(sddmax, am2) + fmaxf(sddmin, am2)) : 0.f;

      if (it < QP_ITERS - 1) {
        const float vn = lnew + ssv[rr]
                       + D0 + (D1m - D1) * invT + (D2m2 - 2.f * D2m1 + D2) * invT2;
        const _Float16 vh16 = (_Float16)vn;
        vhs[rl][j] = vh16;
        vls[rl][j] = (_Float16)((vn - (float)vh16) * LSCALE);
      } else {
        out[(size_t)gr * NUMV + j] = x0;
      }

      float a = res2, b = fps2, c = fpl2;
      for (int o = 32; o > 0; o >>= 1) {
        a += __shfl_down(a, o);
        b += __shfl_down(b, o);
        c += __shfl_down(c, o);
      }
      if (lane == 0) { red[wave][rr][0] = a; red[wave][rr][1] = b; red[wave][rr][2] = c; }
    }
    __syncthreads();    // red + vhs/vls ready; xp consumed

    if (tid < 16) {
      const int rl = tid, hf = rl >> 2, rr = rl & 3;
      const int w0 = hf * 4;
      const float r2 = red[w0][rr][0] + red[w0 + 1][rr][0] + red[w0 + 2][rr][0] + red[w0 + 3][rr][0];
      const float s2 = red[w0][rr][1] + red[w0 + 1][rr][1] + red[w0 + 2][rr][1] + red[w0 + 3][rr][1];
      const float l2 = red[w0][rr][2] + red[w0 + 1][rr][2] + red[w0 + 2][rr][2] + red[w0 + 3][rr][2];
      const float pr = sqrtf(r2);
      const float fp = sqrtf(s2) + sqrtf(l2);
      out[primOff + (size_t)it * B + m0 + rl] = pr;
      out[fpOff + (size_t)it * B + m0 + rl] = fp;
      accP += pr; accF += fp;
    }
    // swap x buffers
    float (*t)[264] = xc; xc = xp; xp = t;
  }
  if (tid < 16) {
    out[accPOff + m0 + tid] = accP * (1.f / QP_ITERS);
    out[accFOff + m0 + tid] = accF * (1.f / QP_ITERS);
  }
}

extern "C" void kernel_launch(void* const* d_in, const int* in_sizes, int n_in,
                              void* d_out, int out_size, void* d_ws, size_t ws_size,
                              hipStream_t stream)
{
  const float* inp = (const float*)d_in[0];       // [B][260]
  const float* sinit = (const float*)d_in[1];     // [B][1]
  const float* ssamp = (const float*)d_in[2];     // [B][256]
  const float* p_smax = (const float*)d_in[3];
  const float* p_smin = (const float*)d_in[4];
  const float* p_sdmax = (const float*)d_in[5];
  const float* p_sdmin = (const float*)d_in[6];
  const float* p_sddmax = (const float*)d_in[7];
  const float* p_sddmin = (const float*)d_in[8];
  const float* W1 = (const float*)d_in[11];       // [260][1024]
  const float* b1 = (const float*)d_in[12];       // [1024]
  const float* W2 = (const float*)d_in[13];       // [1024][1786]
  const float* b2 = (const float*)d_in[14];       // [1786]
  float* out = (float*)d_out;

  const int B = in_sizes[1];                      // 4096
  const int IND = in_sizes[9];                    // 260
  const int H = in_sizes[12];                     // 1024
  const int OUTN = in_sizes[14];                  // 1786
  const int KP1 = 288;                            // GEMM1 padded K (9 x 32)

  char* ws = (char*)d_ws;
  float* NO = (float*)ws;                                      // [B][1792] fp32
  char* p = ws + (size_t)B * NO_LD * 4;                        // 29,360,128
  _Float16* hH = (_Float16*)p;                                 // [B][1024] fp16
  char* q = p + (size_t)B * H * 2;                             // 37,748,736
  _Float16* W2T = (_Float16*)q;                                // [1786][1024] fp16
  char* q2 = q + (size_t)OUTN * H * 2;                         // 41,406,464
  _Float16* W1T = (_Float16*)q2;                               // [1024][288] fp16 (padded)
  _Float16* hA = (_Float16*)(q2 + (size_t)H * KP1 * 2);        // 41,996,288: [4096][288] fp16
  char* r4 = ws + 46137344;                                    // 46,137,344
  _Float16* Gh = (_Float16*)r4;                                // [256][256] fp16
  _Float16* Gl = (_Float16*)(r4 + 131072);                     // [256][256] fp16 (x2048)
  float* zc = (float*)(r4 + 262144);                           // [256] fp32

  prep<<<PREP_G + PREP_T1 + PREP_T2 + PREP_CV, 256, 0, stream>>>(
      Gh, Gl, zc, W1, W1T, W2, W2T, inp, hA, IND, OUTN);
  {
    dim3 g(B / 128, H / 128);
    mfma_gemm32<<<g, 256, 0, stream>>>(hA, W1T, b1, hH, KP1, H);
  }
  {
    dim3 g(B / 128, (OUTN + 127) / 128);
    mfma_gemm64<<<g, 256, 0, stream>>>(hH, W2T, b2, NO, B, OUTN, H, H, H, NO_LD);
  }
  qp_solve5<<<B / 16, 1024, 0, stream>>>(Gh, Gl, sinit, zc, NO, ssamp,
                                         p_smax, p_smin, p_sdmax, p_sdmin,
                                         p_sddmax, p_sddmin, out, B);
}

// Round 30
// 118.154 us; speedup vs baseline: 1.3000x; 1.0091x over previous
//
#include <hip/hip_runtime.h>
#include <cstddef>

// learned_qp_solver: B=4096, NUM=256, NC=1530, IND=260, H=1024, OUT=1786, 5 iters.
//
//   KKT solve closed form:  x = G v + (b_eq/z0) z,  G = C^{-1} - z z^T / z0 (symmetric)
//   MLP on matrix cores: v_mfma_f32_16x16x32_f16 (BK=32 GEMM1 / BK=64 GEMM2).
//   Solve: scaled split-fp16 (Gl,Vl x2048 dodge fp16 denormal flush in MFMA).
//   G build: U = L^{-1} at COMPILE TIME (constexpr quarters); gemm_g on MFMA.
//   qp_solve5: round-25 exact (frozen; rounds 17-26: all variants 76-87us).
//   Round-27 (validated +9.6us): GEMM2 global_load_lds + both-sides XOR swizzle.
//   Round-28 (validated +7.2us): split_u folded into gemm_g; GEMM1 B-side gload_lds.
//   Round-29 (validated +16.2us): prep fused to one dispatch; GEMM1 both-sides
//   gload_lds with hA fp16 [B][288] zero-padded.
//   Round-30: dependency-aware dispatch re-org. GEMM1 needs only W1T+hA, but
//   waited on ALL of prep (incl. W2T transpose = 1792 blocks + gemm_g = 128).
//   Split: dispatch1 = {W1T + hA} (544 blocks); dispatch2 = {GEMM1 (first in
//   bid order) + gemm_g + W2T} -> independent work overlaps GEMM1's MFMA
//   blocks instead of serializing before them. Bodies byte-identical; only
//   block-id routing changed.
//
// ws layout (bytes), ~46.7 MB:
//   [0,          29360128)  NO   fp32 [B][1792]
//   [29360128,   37748736)  hH   fp16 [B][1024]
//   [37748736,   41406464)  W2T  fp16 [1786][1024]
//   [41406464,   41996288)  W1T  fp16 [1024][288]  (zero-padded K)
//   [41996288,   44355584)  hA   fp16 [4096][288]  (zero-padded K)
//   [46137344,   46268416)  Gh   fp16 [256][256]
//   [46268416,   46399488)  Gl   fp16 [256][256]  (scaled x2048)
//   [46399488,   46400512)  zc   fp32 [256]

#define NUMV 256
#define QP_ITERS 5
#define NO_LD 1792
#define LSCALE 2048.0f
#define INV_LSCALE (1.0f / 2048.0f)

typedef _Float16 f16x4 __attribute__((ext_vector_type(4)));
typedef _Float16 f16x8 __attribute__((ext_vector_type(8)));
typedef float f32x4 __attribute__((ext_vector_type(4)));

// ---------------- compile-time pentadiagonal Cholesky tables ----------------
struct FacT {
  double invd[256];
  double l1[257];
  double l2[258];
  double z[256];
  float  zcf[256];
};

constexpr double csqrt_(double x) {
  double g = (x > 1.0) ? x : 1.0;
  for (int i = 0; i < 64; ++i) g = 0.5 * (g + x / g);
  return g;
}

constexpr FacT make_fac() {
  FacT f{};
  const double T = 0.05, a = 1.0 / (T * T), b2 = a * a;
  double c0[256] = {}, c1[255] = {}, c2[254] = {};
  double dd[256] = {}, l1[256] = {}, l2[256] = {};
  for (int j = 0; j < 256; j++) {
    double cd1 = (j == 0 || j == 255) ? 1.0 : 2.0;
    double cd2 = (j == 0 || j == 255) ? 1.0 : ((j == 1 || j == 254) ? 5.0 : 6.0);
    c0[j] = 3.0 + 2.0 * a * cd1 + 2.0 * b2 * cd2;
  }
  for (int j = 0; j < 255; j++) c1[j] = -2.0 * a + 2.0 * b2 * ((j == 0 || j == 254) ? -2.0 : -4.0);
  for (int j = 0; j < 254; j++) c2[j] = 2.0 * b2;
  dd[0] = csqrt_(c0[0]); l1[0] = 0.0; l2[0] = 0.0;
  l1[1] = c1[0] / dd[0]; l2[1] = 0.0;
  dd[1] = csqrt_(c0[1] - l1[1] * l1[1]);
  for (int j = 2; j < 256; j++) {
    l2[j] = c2[j - 2] / dd[j - 2];
    l1[j] = (c1[j - 1] - l2[j] * l1[j - 1]) / dd[j - 1];
    dd[j] = csqrt_(c0[j] - l1[j] * l1[j] - l2[j] * l2[j]);
  }
  for (int j = 0; j < 256; j++) f.invd[j] = 1.0 / dd[j];
  for (int j = 0; j < 256; j++) f.l1[j] = l1[j];
  f.l1[256] = 0.0;
  for (int j = 0; j < 256; j++) f.l2[j] = l2[j];
  f.l2[256] = 0.0; f.l2[257] = 0.0;
  double w[256] = {}, zz[256] = {};
  w[0] = 1.0 / dd[0];
  w[1] = (-l1[1] * w[0]) / dd[1];
  for (int j = 2; j < 256; j++) w[j] = (-l1[j] * w[j - 1] - l2[j] * w[j - 2]) / dd[j];
  zz[255] = w[255] / dd[255];
  zz[254] = (w[254] - l1[255] * zz[255]) / dd[254];
  for (int j = 253; j >= 0; j--)
    zz[j] = (w[j] - l1[j + 1] * zz[j + 1] - l2[j + 2] * zz[j + 2]) / dd[j];
  for (int j = 0; j < 256; j++) f.z[j] = zz[j];
  for (int j = 0; j < 256; j++) f.zcf[j] = (float)(zz[j] / zz[0]);
  return f;
}

constexpr FacT FAC_HOST = make_fac();
__constant__ FacT FAC = FAC_HOST;

// ---- compile-time U = L^{-1}: quarter (64 columns) per constexpr evaluation ----
struct UQ { float u[64][256]; };

constexpr UQ make_uq(int cbase) {
  UQ q{};
  const double T = 0.05, a = 1.0 / (T * T), b2 = a * a;
  double c0a[256] = {}, c1a[255] = {}, c2a[254] = {};
  double dd[256] = {}, l1[256] = {}, l2[256] = {};
  for (int j = 0; j < 256; j++) {
    double cd1 = (j == 0 || j == 255) ? 1.0 : 2.0;
    double cd2 = (j == 0 || j == 255) ? 1.0 : ((j == 1 || j == 254) ? 5.0 : 6.0);
    c0a[j] = 3.0 + 2.0 * a * cd1 + 2.0 * b2 * cd2;
  }
  for (int j = 0; j < 255; j++) c1a[j] = -2.0 * a + 2.0 * b2 * ((j == 0 || j == 254) ? -2.0 : -4.0);
  for (int j = 0; j < 254; j++) c2a[j] = 2.0 * b2;
  dd[0] = csqrt_(c0a[0]); l1[0] = 0.0; l2[0] = 0.0;
  l1[1] = c1a[0] / dd[0]; l2[1] = 0.0;
  dd[1] = csqrt_(c0a[1] - l1[1] * l1[1]);
  for (int j = 2; j < 256; j++) {
    l2[j] = c2a[j - 2] / dd[j - 2];
    l1[j] = (c1a[j - 1] - l2[j] * l1[j - 1]) / dd[j - 1];
    dd[j] = csqrt_(c0a[j] - l1[j] * l1[j] - l2[j] * l2[j]);
  }
  for (int c = cbase; c < cbase + 64; ++c) {
    double w1 = 0.0, w2 = 0.0;
    for (int j = c; j < 256; ++j) {
      const double rhs = (j == c) ? 1.0 : 0.0;
      const double wj = (rhs - l1[j] * w1 - l2[j] * w2) / dd[j];
      q.u[c - cbase][j] = (float)wj;
      w2 = w1; w1 = wj;
    }
  }
  return q;
}

constexpr UQ UQ0_H = make_uq(0);
constexpr UQ UQ1_H = make_uq(64);
constexpr UQ UQ2_H = make_uq(128);
constexpr UQ UQ3_H = make_uq(192);
__constant__ UQ UFQ0 = UQ0_H;
__constant__ UQ UFQ1 = UQ1_H;
__constant__ UQ UFQ2 = UQ2_H;
__constant__ UQ UFQ3 = UQ3_H;

__device__ __forceinline__ const float* uq_row(int c) {
  if (c < 64)  return UFQ0.u[c];
  if (c < 128) return UFQ1.u[c - 64];
  if (c < 192) return UFQ2.u[c - 128];
  return UFQ3.u[c - 192];
}

// identical arithmetic to the original split_u conversion
__device__ __forceinline__ void split8(const float* __restrict__ w, f16x8& h, f16x8& l) {
#pragma unroll
  for (int e = 0; e < 8; e++) {
    const float x = w[e];
    const _Float16 hh = (_Float16)x;
    h[e] = hh;
    l[e] = (_Float16)((x - (float)hh) * LSCALE);
  }
}

// ---- gemm_g body (round-28 exact, parameterized block coords; 64 threads) ----
__device__ void gemm_g_body(
    _Float16* __restrict__ Gh, _Float16* __restrict__ Gl, float* __restrict__ zc,
    int gx, int gy, int lane)
{
  const int lr = lane & 15, lg = lane >> 4;
  const int m0 = gx * 16, n0 = gy * 32;
  if (gx == 0 && gy == 0) {
    for (int t = lane; t < 256; t += 64) zc[t] = FAC.zcf[t];
  }
  f32x4 accH[2], accL[2];
#pragma unroll
  for (int nf = 0; nf < 2; nf++) { accH[nf] = (f32x4)0.0f; accL[nf] = (f32x4)0.0f; }
  const float* arow = uq_row(m0 + lr);
  const float* brow0 = uq_row(n0 + lr);
  const float* brow1 = uq_row(n0 + 16 + lr);
#pragma unroll 2
  for (int k0 = 0; k0 < 256; k0 += 32) {
    f16x8 ah, al;
    split8(arow + k0 + lg * 8, ah, al);
#pragma unroll
    for (int nf = 0; nf < 2; nf++) {
      f16x8 bh, bl;
      split8((nf ? brow1 : brow0) + k0 + lg * 8, bh, bl);
      accH[nf] = __builtin_amdgcn_mfma_f32_16x16x32_f16(ah, bh, accH[nf], 0, 0, 0);
      accL[nf] = __builtin_amdgcn_mfma_f32_16x16x32_f16(ah, bl, accL[nf], 0, 0, 0);
      accL[nf] = __builtin_amdgcn_mfma_f32_16x16x32_f16(al, bh, accL[nf], 0, 0, 0);
    }
  }
  const int row0 = m0 + lg * 4;
#pragma unroll
  for (int nf = 0; nf < 2; nf++) {
    const int col = n0 + nf * 16 + lr;
    const double zcd = FAC.z[col] / FAC.z[0];
#pragma unroll
    for (int r = 0; r < 4; r++) {
      const int row = row0 + r;
      const float g = accH[nf][r] + accL[nf][r] * INV_LSCALE
                    - (float)(FAC.z[row] * zcd);
      const _Float16 gh = (_Float16)g;
      Gh[(size_t)row * 256 + col] = gh;
      Gl[(size_t)row * 256 + col] = (_Float16)((g - (float)gh) * LSCALE);
    }
  }
}

// ---- transpose body (round-28 exact, 1-D 256 threads, parameterized coords) ----
__device__ void transpose_body(
    const float* __restrict__ in, _Float16* __restrict__ out,
    int K, int N, int KP, int bx, int by, int tid)
{
  __shared__ float t[32][33];
  const int bk = bx * 32, bn = by * 32;
  const int x = tid & 31, y = tid >> 5;
  for (int yy = y; yy < 32; yy += 8) {
    const int k = bk + yy, n = bn + x;
    t[yy][x] = (k < K && n < N) ? in[(size_t)k * N + n] : 0.f;
  }
  __syncthreads();
  for (int yy = y; yy < 32; yy += 8) {
    const int n = bn + yy, k = bk + x;
    if (n < N && k < KP) out[(size_t)n * KP + k] = (_Float16)t[x][yy];
  }
}

// ---- GEMM1 body (round-29 exact, parameterized block coords; 256 threads) ----
// A = hA fp16 [4096][288] zero-padded, B = W1T fp16 [1024][288] zero-padded ->
// 16B loads at k0+kswz (max 280+8=288) never cross a row, never read garbage.
// chunk = 16 rows x 32 f16 = 1KB; lane l -> row l>>2, source k pre-swizzled
// 8*((l&3)^((l>>2)&3)); reads XOR (r&3)<<3.
__device__ void gemm1_body(
    const _Float16* __restrict__ A, const _Float16* __restrict__ Bt,
    const float* __restrict__ bias, _Float16* __restrict__ C,
    int KP, int ldc, int bx, int by, int tid)
{
  __shared__ _Float16 At[128][32];
  __shared__ _Float16 Bs[128][32];
  const int lane = tid & 63, wid = tid >> 6;
  const int wr = wid >> 1, wc = wid & 1;
  const int lrow = lane & 15, lb = lane >> 4;
  const int m0 = bx * 128, n0 = by * 128;
  const int rl4 = lane >> 2;
  const int kswz = 8 * ((lane & 3) ^ (rl4 & 3));

  f32x4 acc[4][4];
#pragma unroll
  for (int i = 0; i < 4; i++)
#pragma unroll
    for (int j = 0; j < 4; j++) acc[i][j] = (f32x4)0.0f;

  const int nsteps = KP >> 5;
  for (int t = 0; t < nsteps; ++t) {
    const int k0 = t * 32;
#pragma unroll
    for (int c = 0; c < 2; ++c) {
      const int ci = wid * 2 + c;                 // chunk 0..7 (wave-uniform)
      const _Float16* asrc = &A[(size_t)(m0 + ci * 16 + rl4) * KP + k0 + kswz];
      const _Float16* bsrc = &Bt[(size_t)(n0 + ci * 16 + rl4) * KP + k0 + kswz];
      __builtin_amdgcn_global_load_lds(
          (const __attribute__((address_space(1))) void*)asrc,
          (__attribute__((address_space(3))) void*)(&At[ci * 16][0]), 16, 0, 0);
      __builtin_amdgcn_global_load_lds(
          (const __attribute__((address_space(1))) void*)bsrc,
          (__attribute__((address_space(3))) void*)(&Bs[ci * 16][0]), 16, 0, 0);
    }
    __syncthreads();
    f16x8 af[4], bf[4];
#pragma unroll
    for (int i = 0; i < 4; i++) {
      const int r = wr * 64 + i * 16 + lrow;
      af[i] = *reinterpret_cast<const f16x8*>(&At[r][(lb * 8) ^ ((r & 3) << 3)]);
    }
#pragma unroll
    for (int j = 0; j < 4; j++) {
      const int r = wc * 64 + j * 16 + lrow;
      bf[j] = *reinterpret_cast<const f16x8*>(&Bs[r][(lb * 8) ^ ((r & 3) << 3)]);
    }
#pragma unroll
    for (int i = 0; i < 4; i++)
#pragma unroll
      for (int j = 0; j < 4; j++)
        acc[i][j] = __builtin_amdgcn_mfma_f32_16x16x32_f16(af[i], bf[j], acc[i][j], 0, 0, 0);
    __syncthreads();
  }
#pragma unroll
  for (int i = 0; i < 4; i++) {
#pragma unroll
    for (int j = 0; j < 4; j++) {
      const int gcol = n0 + wc * 64 + j * 16 + lrow;
      const float bv = bias[gcol];
#pragma unroll
      for (int r = 0; r < 4; r++) {
        const int grow = m0 + wr * 64 + i * 16 + lb * 4 + r;
        const float v = fmaxf(acc[i][j][r] + bv, 0.f);
        C[(size_t)grow * ldc + gcol] = (_Float16)v;
      }
    }
  }
}

// ---- dispatch 1: only what GEMM1 depends on: W1->W1T | inp->hA pad ----
#define P1_T1 288   // W1T: (288/32=9, 1024/32=32)
#define P1_CV 256   // hA: 4096/16 rows per block
__global__ __launch_bounds__(256) void prep1(
    const float* __restrict__ W1, _Float16* __restrict__ W1T,
    const float* __restrict__ inp, _Float16* __restrict__ hA, int IND)
{
  const int bid = blockIdx.x, tid = threadIdx.x;
  if (bid < P1_T1) {
    transpose_body(W1, W1T, IND, 1024, 288, bid % 9, bid / 9, tid);
  } else {
    const int r0 = (bid - P1_T1) * 16;
    for (int idx = tid; idx < 16 * 288; idx += 256) {
      const int r = r0 + idx / 288, c = idx % 288;
      hA[(size_t)r * 288 + c] =
          (c < IND) ? (_Float16)inp[(size_t)r * IND + c] : (_Float16)0.f;
    }
  }
}

// ---- dispatch 2: GEMM1 (first in bid order -> starts immediately) + the
// GEMM1-independent prep (gemm_g + W2 transpose) overlapping it ----
#define G1_BLKS 256    // GEMM1: (32 x 8)
#define GG_BLKS 128    // gemm_g: (16,8)
#define T2_BLKS 1792   // W2T: (1024/32=32, 1792/32=56)
__global__ __launch_bounds__(256) void gemm1_fused(
    const _Float16* __restrict__ hA, const _Float16* __restrict__ W1T,
    const float* __restrict__ b1, _Float16* __restrict__ hH,
    _Float16* __restrict__ Gh, _Float16* __restrict__ Gl, float* __restrict__ zc,
    const float* __restrict__ W2, _Float16* __restrict__ W2T, int OUTN)
{
  const int bid = blockIdx.x, tid = threadIdx.x;
  if (bid < G1_BLKS) {
    gemm1_body(hA, W1T, b1, hH, 288, 1024, bid & 31, bid >> 5, tid);
  } else if (bid < G1_BLKS + GG_BLKS) {
    const int i = bid - G1_BLKS;
    if (tid < 64) gemm_g_body(Gh, Gl, zc, i & 15, i >> 4, tid);
  } else {
    const int i = bid - G1_BLKS - GG_BLKS;
    transpose_body(W2, W2T, 1024, OUTN, 1024, i & 31, i >> 5, tid);
  }
}

// ---------------- MFMA GEMM BK=64 (fp16 A, K%64==0, M%128==0, fp32 out): GEMM2 ----
// Round-27 (validated +9.6us): global_load_lds width=16 staging + both-sides XOR
// swizzle. B n-tail garbage only contaminates discarded output cols (gcol<Nv).
__global__ __launch_bounds__(256) void mfma_gemm64(
    const _Float16* __restrict__ A, const _Float16* __restrict__ Bt,
    const float* __restrict__ bias, float* __restrict__ C,
    int M, int Nv, int K, int lda, int ldk, int ldc)
{
  __shared__ _Float16 At[128][64];
  __shared__ _Float16 Bs[128][64];
  const int tid = threadIdx.x;
  const int lane = tid & 63, wid = tid >> 6;
  const int wr = wid >> 1, wc = wid & 1;
  const int lrow = lane & 15, lb = lane >> 4;
  const int m0 = blockIdx.x * 128, n0 = blockIdx.y * 128;

  const int srow8 = lane >> 3;                 // row within chunk (0..7)
  const int kswz = 8 * ((lane & 7) ^ srow8);   // pre-swizzled k offset (f16 units)

  f32x4 acc[4][4];
#pragma unroll
  for (int i = 0; i < 4; i++)
#pragma unroll
    for (int j = 0; j < 4; j++) acc[i][j] = (f32x4)0.0f;

  const int nsteps = K >> 6;
  for (int t = 0; t < nsteps; ++t) {
    const int k0 = t * 64;
#pragma unroll
    for (int c = 0; c < 4; ++c) {
      const int ci = wid * 4 + c;              // chunk 0..15 (wave-uniform)
      const int row = ci * 8 + srow8;
      const _Float16* asrc = &A[(size_t)(m0 + row) * lda + k0 + kswz];
      const _Float16* bsrc = &Bt[(size_t)(n0 + row) * ldk + k0 + kswz];
      __builtin_amdgcn_global_load_lds(
          (const __attribute__((address_space(1))) void*)asrc,
          (__attribute__((address_space(3))) void*)(&At[ci * 8][0]), 16, 0, 0);
      __builtin_amdgcn_global_load_lds(
          (const __attribute__((address_space(1))) void*)bsrc,
          (__attribute__((address_space(3))) void*)(&Bs[ci * 8][0]), 16, 0, 0);
    }
    __syncthreads();
#pragma unroll
    for (int h = 0; h < 2; h++) {
      f16x8 af[4], bf[4];
#pragma unroll
      for (int i = 0; i < 4; i++) {
        const int r = wr * 64 + i * 16 + lrow;
        af[i] = *reinterpret_cast<const f16x8*>(
            &At[r][(h * 32 + lb * 8) ^ ((r & 7) << 3)]);
      }
#pragma unroll
      for (int j = 0; j < 4; j++) {
        const int r = wc * 64 + j * 16 + lrow;
        bf[j] = *reinterpret_cast<const f16x8*>(
            &Bs[r][(h * 32 + lb * 8) ^ ((r & 7) << 3)]);
      }
#pragma unroll
      for (int i = 0; i < 4; i++)
#pragma unroll
        for (int j = 0; j < 4; j++)
          acc[i][j] = __builtin_amdgcn_mfma_f32_16x16x32_f16(af[i], bf[j], acc[i][j], 0, 0, 0);
    }
    __syncthreads();
  }
#pragma unroll
  for (int i = 0; i < 4; i++) {
#pragma unroll
    for (int j = 0; j < 4; j++) {
      const int gcol = n0 + wc * 64 + j * 16 + lrow;
      if (gcol < Nv) {
        const float bv = bias[gcol];
#pragma unroll
        for (int r = 0; r < 4; r++) {
          const int grow = m0 + wr * 64 + i * 16 + lb * 4 + r;
          C[(size_t)grow * ldc + gcol] = acc[i][j][r] + bv;
        }
      }
    }
  }
}

// ---- ALL 5 QP iterations in one kernel (init_v fused). Block = 16 rows,
// 1024 threads (16 waves). Wave w = 16-col MFMA slice; Gh hoisted in registers
// (32 VGPRs), Gl read from L2 per iteration (round-25 exact, measured best);
// update thread = (j = tid&255, half = tid>>8) x 4 rows. 2 barriers/iter.
__global__ __launch_bounds__(1024) void qp_solve5(
    const _Float16* __restrict__ Gh, const _Float16* __restrict__ Gl,
    const float* __restrict__ beq, const float* __restrict__ zc,
    const float* __restrict__ NO, const float* __restrict__ ss,
    const float* __restrict__ p_smax, const float* __restrict__ p_smin,
    const float* __restrict__ p_sdmax, const float* __restrict__ p_sdmin,
    const float* __restrict__ p_sddmax, const float* __restrict__ p_sddmin,
    float* __restrict__ out, int B)
{
  __shared__ float xsA[16][264], xsB[16][264];
  __shared__ _Float16 vhs[16][264], vls[16][264];
  __shared__ float zcs[256], beqs[16];
  __shared__ float red[16][4][3];
  const int tid = threadIdx.x;
  const int wave = tid >> 6, lane = tid & 63;
  const int lr = lane & 15, lg = lane >> 4;
  const int m0 = blockIdx.x * 16;
  const int n0 = wave * 16;
  const int j = tid & 255, half = tid >> 8;    // half in 0..3

  const float smax = *p_smax, smin = *p_smin;
  const float sdmax = *p_sdmax, sdmin = *p_sdmin;
  const float sddmax = *p_sddmax, sddmin = *p_sddmin;
  const float K0 = smax + smin, K1 = sdmax + sdmin, K2 = sddmax + sddmin;
  const float invT = 20.f, invT2 = 400.f;
  const bool h1 = j < 255, h2 = j < 254;

  // ---- hoist Gh only (32 VGPRs) for this wave's 16-col slice ----
  f16x8 gh_r[8];
#pragma unroll
  for (int kk = 0; kk < 8; kk++) {
    const size_t bidx = (size_t)(n0 + lr) * 256 + kk * 32 + lg * 8;
    gh_r[kk] = *reinterpret_cast<const f16x8*>(&Gh[bidx]);
  }

  // ---- per-thread persistent state + FUSED init_v (round-8-validated formula) ----
  float lamr[4], ssv[4];
#pragma unroll
  for (int rr = 0; rr < 4; rr++) {
    const int rl = half * 4 + rr;
    const int gr = m0 + rl;
    const float* no = NO + (size_t)gr * NO_LD;
    ssv[rr] = ss[(size_t)gr * NUMV + j];
    lamr[rr] = no[j];
    const float D0 = K0 - fmaxf(0.f, no[256 + j]) + fmaxf(0.f, no[512 + j]);
    const float D1j = h1 ? (K1 - fmaxf(0.f, no[768 + j]) + fmaxf(0.f, no[1023 + j])) : 0.f;
    const float D1m = (j >= 1) ? (K1 - fmaxf(0.f, no[768 + j - 1]) + fmaxf(0.f, no[1023 + j - 1])) : 0.f;
    const float D2j = h2 ? (K2 - fmaxf(0.f, no[1278 + j]) + fmaxf(0.f, no[1532 + j])) : 0.f;
    const float D2m1 = (j >= 1 && h1) ? (K2 - fmaxf(0.f, no[1278 + j - 1]) + fmaxf(0.f, no[1532 + j - 1])) : 0.f;
    const float D2m2 = (j >= 2) ? (K2 - fmaxf(0.f, no[1278 + j - 2]) + fmaxf(0.f, no[1532 + j - 2])) : 0.f;
    const float vn = lamr[rr] + ssv[rr]
                   + D0 + (D1m - D1j) * invT + (D2m2 - 2.f * D2m1 + D2j) * invT2;
    const _Float16 vh16 = (_Float16)vn;
    vhs[rl][j] = vh16;
    vls[rl][j] = (_Float16)((vn - (float)vh16) * LSCALE);
  }
  if (tid < 256) zcs[tid] = zc[tid];
  if (tid < 16) {
    beqs[tid] = beq[m0 + tid];
    xsA[tid][0] = 0.f; xsA[tid][1] = 0.f; xsA[tid][258] = 0.f; xsA[tid][259] = 0.f;
    xsB[tid][0] = 0.f; xsB[tid][1] = 0.f; xsB[tid][258] = 0.f; xsB[tid][259] = 0.f;
  }
  float accP = 0.f, accF = 0.f;

  const size_t primOff = (size_t)B * NUMV;
  const size_t fpOff = primOff + (size_t)QP_ITERS * B;
  const size_t accPOff = fpOff + (size_t)QP_ITERS * B;
  const size_t accFOff = accPOff + (size_t)B;

  float (*xc)[264] = xsA;
  float (*xp)[264] = xsB;

  __syncthreads();    // staged vhs/vls/zcs/beqs ready

  for (int it = 0; it < QP_ITERS; ++it) {
    // ---- Phase 1: MFMA solve (validated split-fp16 path; Gh regs, Gl L2) ----
    f32x4 accH = (f32x4)0.0f, accL = (f32x4)0.0f;
#pragma unroll
    for (int kk = 0; kk < 8; kk++) {
      const f16x8 ah = *reinterpret_cast<const f16x8*>(&vhs[lr][kk * 32 + lg * 8]);
      const f16x8 al = *reinterpret_cast<const f16x8*>(&vls[lr][kk * 32 + lg * 8]);
      const f16x8 bl = *reinterpret_cast<const f16x8*>(
          &Gl[(size_t)(n0 + lr) * 256 + kk * 32 + lg * 8]);
      accH = __builtin_amdgcn_mfma_f32_16x16x32_f16(ah, gh_r[kk], accH, 0, 0, 0);
      accL = __builtin_amdgcn_mfma_f32_16x16x32_f16(ah, bl, accL, 0, 0, 0);
      accL = __builtin_amdgcn_mfma_f32_16x16x32_f16(al, gh_r[kk], accL, 0, 0, 0);
    }
    {
      const int r0l = lg * 4;
      const int col = n0 + lr;
      const float zv = zcs[col];
#pragma unroll
      for (int r = 0; r < 4; r++)
        xc[r0l + r][col + 2] = accH[r] + accL[r] * INV_LSCALE + beqs[r0l + r] * zv;
    }
    __syncthreads();    // x ready; previous red consumed

    // ---- Phase 2: update (validated local-recompute stencils), 4 rows/thread ----
#pragma unroll
    for (int rr = 0; rr < 4; rr++) {
      const int rl = half * 4 + rr;
      const int gr = m0 + rl;
      const float xm2 = xc[rl][j];
      const float xm1 = xc[rl][j + 1];
      const float x0  = xc[rl][j + 2];
      const float x1  = xc[rl][j + 3];
      const float x2  = xc[rl][j + 4];

      const float vj = (x1 - x0) * invT;
      const float aj = (x2 - 2.f * x1 + x0) * invT2;
      const float vm1 = (x0 - xm1) * invT;
      const float am1 = (x1 - 2.f * x0 + xm1) * invT2;
      const float am2 = (x0 - 2.f * xm1 + xm2) * invT2;

      const float rv0a = fmaxf(0.f, x0 - smax), rv0b = fmaxf(0.f, smin - x0);
      const float E0 = rv0a - rv0b;
      float rv1a = 0.f, rv1b = 0.f, rv2a = 0.f, rv2b = 0.f, E1 = 0.f, E2 = 0.f;
      if (h1) { rv1a = fmaxf(0.f, vj - sdmax); rv1b = fmaxf(0.f, sdmin - vj); E1 = rv1a - rv1b; }
      if (h2) { rv2a = fmaxf(0.f, aj - sddmax); rv2b = fmaxf(0.f, sddmin - aj); E2 = rv2a - rv2b; }
      float res2 = rv0a * rv0a + rv0b * rv0b + rv1a * rv1a + rv1b * rv1b
                 + rv2a * rv2a + rv2b * rv2b;

      const float E1m = (j >= 1) ? (fmaxf(0.f, vm1 - sdmax) - fmaxf(0.f, sdmin - vm1)) : 0.f;
      const float E2m1 = (j >= 1 && h1) ? (fmaxf(0.f, am1 - sddmax) - fmaxf(0.f, sddmin - am1)) : 0.f;
      const float E2m2 = (j >= 2) ? (fmaxf(0.f, am2 - sddmax) - fmaxf(0.f, sddmin - am2)) : 0.f;

      const float dl = E0 + (E1m - E1) * invT + (E2m2 - 2.f * E2m1 + E2) * invT2;
      const float lnew = lamr[rr] - dl;
      const float fpl2 = dl * dl;
      lamr[rr] = lnew;

      const float sn0a = fmaxf(0.f, smax - x0), sn0b = fmaxf(0.f, x0 - smin);
      float sn1a = 0.f, sn1b = 0.f, sn2a = 0.f, sn2b = 0.f;
      if (h1) { sn1a = fmaxf(0.f, sdmax - vj); sn1b = fmaxf(0.f, vj - sdmin); }
      if (h2) { sn2a = fmaxf(0.f, sddmax - aj); sn2b = fmaxf(0.f, aj - sddmin); }

      float sp0a, sp0b, sp1a = 0.f, sp1b = 0.f, sp2a = 0.f, sp2b = 0.f;
      if (it == 0) {
        const float* no = NO + (size_t)gr * NO_LD;
        sp0a = fmaxf(0.f, no[256 + j]); sp0b = fmaxf(0.f, no[512 + j]);
        if (h1) { sp1a = fmaxf(0.f, no[768 + j]); sp1b = fmaxf(0.f, no[1023 + j]); }
        if (h2) { sp2a = fmaxf(0.f, no[1278 + j]); sp2b = fmaxf(0.f, no[1532 + j]); }
      } else {
        const float p0 = xp[rl][j + 2], p1 = xp[rl][j + 3], p2 = xp[rl][j + 4];
        const float vp = (p1 - p0) * invT;
        const float ap = (p2 - 2.f * p1 + p0) * invT2;
        sp0a = fmaxf(0.f, smax - p0); sp0b = fmaxf(0.f, p0 - smin);
        if (h1) { sp1a = fmaxf(0.f, sdmax - vp); sp1b = fmaxf(0.f, vp - sdmin); }
        if (h2) { sp2a = fmaxf(0.f, sddmax - ap); sp2b = fmaxf(0.f, ap - sddmin); }
      }
      const float d0a = sp0a - sn0a, d0b = sp0b - sn0b;
      const float d1a = sp1a - sn1a, d1b = sp1b - sn1b;
      const float d2a = sp2a - sn2a, d2b = sp2b - sn2b;
      float fps2 = d0a * d0a + d0b * d0b + d1a * d1a + d1b * d1b
                 + d2a * d2a + d2b * d2b;

      const float D0 = fminf(smax, x0) + fmaxf(smin, x0);
      const float D1 = h1 ? (fminf(sdmax, vj) + fmaxf(sdmin, vj)) : 0.f;
      const float D2 = h2 ? (fminf(sddmax, aj) + fmaxf(sddmin, aj)) : 0.f;
      const float D1m = (j >= 1) ? (fminf(sdmax, vm1) + fmaxf(sdmin, vm1)) : 0.f;
      const float D2m1 = (j >= 1 && h1) ? (fminf(sddmax, am1) + fmaxf(sddmin, am1)) : 0.f;
      const float D2m2 = (j >= 2) ? (fminf(sddmax, am2) + fmaxf(sddmin, am2)) : 0.f;

      if (it < QP_ITERS - 1) {
        const float vn = lnew + ssv[rr]
                       + D0 + (D1m - D1) * invT + (D2m2 - 2.f * D2m1 + D2) * invT2;
        const _Float16 vh16 = (_Float16)vn;
        vhs[rl][j] = vh16;
        vls[rl][j] = (_Float16)((vn - (float)vh16) * LSCALE);
      } else {
        out[(size_t)gr * NUMV + j] = x0;
      }

      float a = res2, b = fps2, c = fpl2;
      for (int o = 32; o > 0; o >>= 1) {
        a += __shfl_down(a, o);
        b += __shfl_down(b, o);
        c += __shfl_down(c, o);
      }
      if (lane == 0) { red[wave][rr][0] = a; red[wave][rr][1] = b; red[wave][rr][2] = c; }
    }
    __syncthreads();    // red + vhs/vls ready; xp consumed

    if (tid < 16) {
      const int rl = tid, hf = rl >> 2, rr = rl & 3;
      const int w0 = hf * 4;
      const float r2 = red[w0][rr][0] + red[w0 + 1][rr][0] + red[w0 + 2][rr][0] + red[w0 + 3][rr][0];
      const float s2 = red[w0][rr][1] + red[w0 + 1][rr][1] + red[w0 + 2][rr][1] + red[w0 + 3][rr][1];
      const float l2 = red[w0][rr][2] + red[w0 + 1][rr][2] + red[w0 + 2][rr][2] + red[w0 + 3][rr][2];
      const float pr = sqrtf(r2);
      const float fp = sqrtf(s2) + sqrtf(l2);
      out[primOff + (size_t)it * B + m0 + rl] = pr;
      out[fpOff + (size_t)it * B + m0 + rl] = fp;
      accP += pr; accF += fp;
    }
    // swap x buffers
    float (*t)[264] = xc; xc = xp; xp = t;
  }
  if (tid < 16) {
    out[accPOff + m0 + tid] = accP * (1.f / QP_ITERS);
    out[accFOff + m0 + tid] = accF * (1.f / QP_ITERS);
  }
}

extern "C" void kernel_launch(void* const* d_in, const int* in_sizes, int n_in,
                              void* d_out, int out_size, void* d_ws, size_t ws_size,
                              hipStream_t stream)
{
  const float* inp = (const float*)d_in[0];       // [B][260]
  const float* sinit = (const float*)d_in[1];     // [B][1]
  const float* ssamp = (const float*)d_in[2];     // [B][256]
  const float* p_smax = (const float*)d_in[3];
  const float* p_smin = (const float*)d_in[4];
  const float* p_sdmax = (const float*)d_in[5];
  const float* p_sdmin = (const float*)d_in[6];
  const float* p_sddmax = (const float*)d_in[7];
  const float* p_sddmin = (const float*)d_in[8];
  const float* W1 = (const float*)d_in[11];       // [260][1024]
  const float* b1 = (const float*)d_in[12];       // [1024]
  const float* W2 = (const float*)d_in[13];       // [1024][1786]
  const float* b2 = (const float*)d_in[14];       // [1786]
  float* out = (float*)d_out;

  const int B = in_sizes[1];                      // 4096
  const int IND = in_sizes[9];                    // 260
  const int H = in_sizes[12];                     // 1024
  const int OUTN = in_sizes[14];                  // 1786
  const int KP1 = 288;                            // GEMM1 padded K (9 x 32)

  char* ws = (char*)d_ws;
  float* NO = (float*)ws;                                      // [B][1792] fp32
  char* p = ws + (size_t)B * NO_LD * 4;                        // 29,360,128
  _Float16* hH = (_Float16*)p;                                 // [B][1024] fp16
  char* q = p + (size_t)B * H * 2;                             // 37,748,736
  _Float16* W2T = (_Float16*)q;                                // [1786][1024] fp16
  char* q2 = q + (size_t)OUTN * H * 2;                         // 41,406,464
  _Float16* W1T = (_Float16*)q2;                               // [1024][288] fp16 (padded)
  _Float16* hA = (_Float16*)(q2 + (size_t)H * KP1 * 2);        // 41,996,288: [4096][288] fp16
  char* r4 = ws + 46137344;                                    // 46,137,344
  _Float16* Gh = (_Float16*)r4;                                // [256][256] fp16
  _Float16* Gl = (_Float16*)(r4 + 131072);                     // [256][256] fp16 (x2048)
  float* zc = (float*)(r4 + 262144);                           // [256] fp32

  prep1<<<P1_T1 + P1_CV, 256, 0, stream>>>(W1, W1T, inp, hA, IND);
  gemm1_fused<<<G1_BLKS + GG_BLKS + T2_BLKS, 256, 0, stream>>>(
      hA, W1T, b1, hH, Gh, Gl, zc, W2, W2T, OUTN);
  {
    dim3 g(B / 128, (OUTN + 127) / 128);
    mfma_gemm64<<<g, 256, 0, stream>>>(hH, W2T, b2, NO, B, OUTN, H, H, H, NO_LD);
  }
  qp_solve5<<<B / 16, 1024, 0, stream>>>(Gh, Gl, sinit, zc, NO, ssamp,
                                         p_smax, p_smin, p_sdmax, p_sdmin,
                                         p_sddmax, p_sddmin, out, B);
}